// Round 1
// baseline (738.495 us; speedup 1.0000x reference)
//
#include <hip/hip_runtime.h>

// ---------------------------------------------------------------------------
// Decoder step: embed gather -> additive attention -> 2-layer LSTM -> fc
// Shapes: B=64, S=128, E=512, H=512, H2=1024, V=32000
// All big GEMMs: bf16 MFMA 16x16x32, weights converted f32->bf16 in-register.
// ---------------------------------------------------------------------------

typedef __attribute__((ext_vector_type(8))) short bf16x8;
typedef __attribute__((ext_vector_type(4))) float f32x4;

__device__ __forceinline__ short f2bf(float f){
  __bf16 h = (__bf16)f;            // RNE convert, lowers to v_cvt on gfx950
  return __builtin_bit_cast(short, h);
}

__device__ __forceinline__ bf16x8 ld8_bf(const float* __restrict__ p){
  float4 v0 = *(const float4*)p;
  float4 v1 = *(const float4*)(p + 4);
  bf16x8 r;
  r[0]=f2bf(v0.x); r[1]=f2bf(v0.y); r[2]=f2bf(v0.z); r[3]=f2bf(v0.w);
  r[4]=f2bf(v1.x); r[5]=f2bf(v1.y); r[6]=f2bf(v1.z); r[7]=f2bf(v1.w);
  return r;
}

__device__ __forceinline__ float fast_tanh(float x){
  x = fminf(fmaxf(x, -15.f), 15.f);
  float t = __expf(2.f * x);
  return (t - 1.f) / (t + 1.f);
}
__device__ __forceinline__ float fast_sig(float x){
  return 1.f / (1.f + __expf(-x));
}

// ---------------------------------------------------------------------------
// C[64,N](ldc) = A1[64,K1] @ W1[N,K1]^T + A2[64,K2] @ W2[N,K2]^T + bias1+bias2
// One wave computes a 64(m) x 16(n) tile. waves = blockDim/64 tiles per block.
// A row stride = K (dense). W row stride = sW (to support column slices).
// ---------------------------------------------------------------------------
__global__ __launch_bounds__(256) void gemm_skinny(
    const float* __restrict__ A1, const float* __restrict__ W1, int K1, int sW1,
    const float* __restrict__ A2, const float* __restrict__ W2, int K2, int sW2,
    const float* __restrict__ bias1, const float* __restrict__ bias2,
    float* __restrict__ C, int ldc)
{
  const int wave  = threadIdx.x >> 6;
  const int lane  = threadIdx.x & 63;
  const int l15   = lane & 15;
  const int lg    = lane >> 4;
  const int waves = blockDim.x >> 6;
  const int nb    = (blockIdx.x * waves + wave) * 16;

  f32x4 acc[4] = {};

  for (int seg = 0; seg < 2; ++seg){
    const float* A  = seg ? A2 : A1;
    const float* W  = seg ? W2 : W1;
    const int    K  = seg ? K2 : K1;
    const int    sW = seg ? sW2 : sW1;
    if (A == nullptr || K <= 0) continue;
    const float* wp = W + (long)(nb + l15) * sW + lg * 8;
    const float* ap = A + (long)l15 * K + lg * 8;
    #pragma unroll 2
    for (int kb = 0; kb < K; kb += 32){
      bf16x8 wf = ld8_bf(wp + kb);
      bf16x8 a0 = ld8_bf(ap + kb);
      bf16x8 a1 = ld8_bf(ap + 16*K + kb);
      bf16x8 a2 = ld8_bf(ap + 32*K + kb);
      bf16x8 a3 = ld8_bf(ap + 48*K + kb);
      acc[0] = __builtin_amdgcn_mfma_f32_16x16x32_bf16(a0, wf, acc[0], 0,0,0);
      acc[1] = __builtin_amdgcn_mfma_f32_16x16x32_bf16(a1, wf, acc[1], 0,0,0);
      acc[2] = __builtin_amdgcn_mfma_f32_16x16x32_bf16(a2, wf, acc[2], 0,0,0);
      acc[3] = __builtin_amdgcn_mfma_f32_16x16x32_bf16(a3, wf, acc[3], 0,0,0);
    }
  }

  float bn = 0.f;
  if (bias1) bn += bias1[nb + l15];
  if (bias2) bn += bias2[nb + l15];
  #pragma unroll
  for (int mt = 0; mt < 4; ++mt){
    #pragma unroll
    for (int r = 0; r < 4; ++r){
      int m = mt*16 + lg*4 + r;
      C[(long)m * ldc + nb + l15] = acc[mt][r] + bn;
    }
  }
}

// ---------------------------------------------------------------------------
// Attention energy: T = enc[8192,1024] @ W_e[512,1024]^T, then
// scores[m] += sum_n v[n]*tanh(T[m,n] + hproj[b(m),n])   (atomic partials)
// grid = (128 m-blocks, 8 n-blocks), 256 threads (4 waves x 16 n each).
// ---------------------------------------------------------------------------
__global__ __launch_bounds__(256) void gemm_energy(
    const float* __restrict__ enc, const float* __restrict__ attn_w,
    const float* __restrict__ hproj, const float* __restrict__ v_w,
    float* __restrict__ scores)
{
  const int wave = threadIdx.x >> 6;
  const int lane = threadIdx.x & 63;
  const int l15  = lane & 15;
  const int lg   = lane >> 4;
  const int mb   = blockIdx.x * 64;
  const int nb   = blockIdx.y * 64 + wave * 16;

  f32x4 acc[4] = {};
  const float* wp = attn_w + (long)(nb + l15) * 2048 + 1024 + lg * 8; // W_e slice
  const float* ap = enc + (long)(mb + l15) * 1024 + lg * 8;
  #pragma unroll 2
  for (int kb = 0; kb < 1024; kb += 32){
    bf16x8 wf = ld8_bf(wp + kb);
    bf16x8 a0 = ld8_bf(ap + kb);
    bf16x8 a1 = ld8_bf(ap + 16*1024 + kb);
    bf16x8 a2 = ld8_bf(ap + 32*1024 + kb);
    bf16x8 a3 = ld8_bf(ap + 48*1024 + kb);
    acc[0] = __builtin_amdgcn_mfma_f32_16x16x32_bf16(a0, wf, acc[0], 0,0,0);
    acc[1] = __builtin_amdgcn_mfma_f32_16x16x32_bf16(a1, wf, acc[1], 0,0,0);
    acc[2] = __builtin_amdgcn_mfma_f32_16x16x32_bf16(a2, wf, acc[2], 0,0,0);
    acc[3] = __builtin_amdgcn_mfma_f32_16x16x32_bf16(a3, wf, acc[3], 0,0,0);
  }

  const float vn = v_w[nb + l15];
  #pragma unroll
  for (int mt = 0; mt < 4; ++mt){
    #pragma unroll
    for (int r = 0; r < 4; ++r){
      int m = mb + mt*16 + lg*4 + r;
      int b = m >> 7;
      float e = fast_tanh(acc[mt][r] + hproj[(long)b*512 + nb + l15]) * vn;
      e += __shfl_xor(e, 1, 16);
      e += __shfl_xor(e, 2, 16);
      e += __shfl_xor(e, 4, 16);
      e += __shfl_xor(e, 8, 16);
      if (l15 == 0) atomicAdd(&scores[m], e);
    }
  }
}

// masked softmax over S=128 per batch row -> attn weights (also to d_out)
__global__ __launch_bounds__(128) void softmax_k(
    const float* __restrict__ scores, const int* __restrict__ mask,
    float* __restrict__ aw)
{
  const int b = blockIdx.x;
  const int s = threadIdx.x;
  float v = scores[b*128 + s];
  if (mask[b*128 + s] == 0) v = -1e10f;
  __shared__ float red[128];
  red[s] = v; __syncthreads();
  for (int d = 64; d > 0; d >>= 1){
    if (s < d) red[s] = fmaxf(red[s], red[s + d]);
    __syncthreads();
  }
  float mx = red[0];
  __syncthreads();
  float e = __expf(v - mx);
  red[s] = e; __syncthreads();
  for (int d = 64; d > 0; d >>= 1){
    if (s < d) red[s] += red[s + d];
    __syncthreads();
  }
  aw[b*128 + s] = e / red[0];
}

// context[b,d] = sum_s aw[b,s] * enc[b,s,d]; writes to x0[:,512+d] and z[:,1024+d]
__global__ __launch_bounds__(256) void context_k(
    const float* __restrict__ aw, const float* __restrict__ enc,
    float* __restrict__ x0, float* __restrict__ z)
{
  const int b  = blockIdx.x;
  const int dd = blockIdx.y * 256 + threadIdx.x;   // 0..1023
  __shared__ float w[128];
  if (threadIdx.x < 128) w[threadIdx.x] = aw[b*128 + threadIdx.x];
  __syncthreads();
  float s = 0.f;
  const float* e = enc + (long)b * 131072 + dd;
  #pragma unroll 4
  for (int si = 0; si < 128; ++si) s += w[si] * e[si * 1024];
  x0[b*1536 + 512 + dd] = s;
  z[b*2560 + 1024 + dd] = s;
}

// embedding gather into x0[:,0:512] and z[:,2048:2560]
__global__ __launch_bounds__(256) void prep_k(
    const int* __restrict__ tok, const float* __restrict__ emb,
    float* __restrict__ x0, float* __restrict__ z)
{
  const int i = blockIdx.x * 256 + threadIdx.x;   // 64*512
  const int b = i >> 9, e = i & 511;
  float v = emb[(long)tok[b] * 512 + e];
  x0[b*1536 + e] = v;
  z[b*2560 + 2048 + e] = v;
}

// LSTM cell epilogue: gates [64,4096] (i,f,g,o) -> h,c ; extra h copy with stride
__global__ __launch_bounds__(256) void lstm_k(
    const float* __restrict__ gates, const float* __restrict__ c_prev,
    float* __restrict__ h_out, float* __restrict__ c_out,
    float* __restrict__ h_copy, int copy_stride)
{
  const int i = blockIdx.x * 256 + threadIdx.x;   // 64*1024
  const int b = i >> 10, n = i & 1023;
  const float* g = gates + (long)b * 4096;
  float iv = fast_sig (g[n]);
  float fv = fast_sig (g[1024 + n]);
  float gv = fast_tanh(g[2048 + n]);
  float ov = fast_sig (g[3072 + n]);
  float c = fv * c_prev[i] + iv * gv;
  float h = ov * fast_tanh(c);
  c_out[i] = c;
  h_out[i] = h;
  h_copy[(long)b * copy_stride + n] = h;
}

extern "C" void kernel_launch(void* const* d_in, const int* in_sizes, int n_in,
                              void* d_out, int out_size, void* d_ws, size_t ws_size,
                              hipStream_t stream)
{
  const int*   tok    = (const int*)  d_in[0];
  const float* hidden = (const float*)d_in[1];
  const float* cell   = (const float*)d_in[2];
  const float* enc    = (const float*)d_in[3];
  const int*   mask   = (const int*)  d_in[4];
  const float* emb    = (const float*)d_in[5];
  const float* attn_w = (const float*)d_in[6];
  const float* attn_b = (const float*)d_in[7];
  const float* v_w    = (const float*)d_in[8];
  const float* w_ih0  = (const float*)d_in[9];
  const float* w_hh0  = (const float*)d_in[10];
  const float* b_ih0  = (const float*)d_in[11];
  const float* b_hh0  = (const float*)d_in[12];
  const float* w_ih1  = (const float*)d_in[13];
  const float* w_hh1  = (const float*)d_in[14];
  const float* b_ih1  = (const float*)d_in[15];
  const float* b_hh1  = (const float*)d_in[16];
  const float* fc_w   = (const float*)d_in[17];
  const float* fc_b   = (const float*)d_in[18];

  float* out  = (float*)d_out;
  float* pred = out;                 // [64,32000]
  float* nh   = out + 2048000;       // [2,64,1024]
  float* nc   = out + 2179072;       // [2,64,1024]
  float* aw   = out + 2310144;       // [64,128]

  float* ws     = (float*)d_ws;
  float* x0     = ws;                // [64,1536] = embedded | context
  float* z      = ws + 98304;        // [64,2560] = h1' | context | embedded
  float* gates0 = ws + 262144;       // [64,4096]
  float* gates1 = ws + 524288;       // [64,4096]
  float* hproj  = ws + 786432;       // [64,512]
  float* scores = ws + 819200;       // [8192]
  float* x1     = ws + 827392;       // [64,1024] = h0'

  hipMemsetAsync(scores, 0, 8192 * sizeof(float), stream);

  prep_k<<<128, 256, 0, stream>>>(tok, emb, x0, z);

  // hproj = h_top @ W_h^T + attn_b   (W_h = attn_w[:, 0:1024])
  gemm_skinny<<<16, 128, 0, stream>>>(hidden + 65536, attn_w, 1024, 2048,
                                      nullptr, nullptr, 0, 0,
                                      attn_b, nullptr, hproj, 512);

  gemm_energy<<<dim3(128, 8), 256, 0, stream>>>(enc, attn_w, hproj, v_w, scores);

  softmax_k<<<64, 128, 0, stream>>>(scores, mask, aw);

  context_k<<<dim3(64, 4), 256, 0, stream>>>(aw, enc, x0, z);

  // layer 0 gates = [x0 | h_prev0] @ [w_ih0 | w_hh0]^T + b_ih0 + b_hh0
  gemm_skinny<<<128, 128, 0, stream>>>(x0, w_ih0, 1536, 1536,
                                       hidden, w_hh0, 1024, 1024,
                                       b_ih0, b_hh0, gates0, 4096);
  lstm_k<<<256, 256, 0, stream>>>(gates0, cell, nh, nc, x1, 1024);

  // layer 1 gates = [h0' | h_prev1] @ [w_ih1 | w_hh1]^T + b_ih1 + b_hh1
  gemm_skinny<<<128, 128, 0, stream>>>(x1, w_ih1, 1024, 1024,
                                       hidden + 65536, w_hh1, 1024, 1024,
                                       b_ih1, b_hh1, gates1, 4096);
  lstm_k<<<256, 256, 0, stream>>>(gates1, cell + 65536, nh + 65536, nc + 65536,
                                  z, 2560);

  // prediction = z @ fc_w^T + fc_b
  gemm_skinny<<<500, 256, 0, stream>>>(z, fc_w, 2560, 2560,
                                       nullptr, nullptr, 0, 0,
                                       fc_b, nullptr, pred, 32000);
}

// Round 2
// 398.633 us; speedup vs baseline: 1.8526x; 1.8526x over previous
//
#include <hip/hip_runtime.h>

// Decoder step: embed -> additive attention -> 2-layer LSTM -> fc
// B=64, S=128, E=512, H=512, H2=1024, V=32000
// GEMMs: bf16 MFMA 16x16x32; A pre-packed bf16, weights f32 cvt in-register.
// Split-K (gridDim.y) into ws partials; consumers fuse the reduction + bias.

typedef __attribute__((ext_vector_type(8))) short bf16x8;
typedef __attribute__((ext_vector_type(4))) float f32x4;

__device__ __forceinline__ short f2bf(float f){
  __bf16 h = (__bf16)f;
  return __builtin_bit_cast(short, h);
}

__device__ __forceinline__ bf16x8 ld8_bf(const float* __restrict__ p){
  float4 v0 = *(const float4*)p;
  float4 v1 = *(const float4*)(p + 4);
  bf16x8 r;
  r[0]=f2bf(v0.x); r[1]=f2bf(v0.y); r[2]=f2bf(v0.z); r[3]=f2bf(v0.w);
  r[4]=f2bf(v1.x); r[5]=f2bf(v1.y); r[6]=f2bf(v1.z); r[7]=f2bf(v1.w);
  return r;
}

__device__ __forceinline__ float fast_tanh(float x){
  x = fminf(fmaxf(x, -15.f), 15.f);
  float t = __expf(2.f * x);
  return (t - 1.f) / (t + 1.f);
}
__device__ __forceinline__ float fast_sig(float x){
  return 1.f / (1.f + __expf(-x));
}

// ---------------------------------------------------------------------------
// P[by][64][N] = A_bf16[64,K] @ [W1|W2][N,:]^T  restricted to k-slice by.
// A is merged bf16 [64][lda]; W1 covers k in [0,K1), W2 covers [K1, ...).
// One wave -> 64m x 16n tile; block = 4 waves = 64 cols.
// ---------------------------------------------------------------------------
__global__ __launch_bounds__(256) void gemm_ws(
    const short* __restrict__ A, int lda,
    const float* __restrict__ W1, int sW1, int K1,
    const float* __restrict__ W2, int sW2,
    int Kslice, float* __restrict__ P, int N)
{
  const int wave = threadIdx.x >> 6;
  const int lane = threadIdx.x & 63;
  const int l15  = lane & 15;
  const int lg   = lane >> 4;
  const int nb   = blockIdx.x * 64 + wave * 16;
  const int k0   = blockIdx.y * Kslice;
  const int k1   = k0 + Kslice;

  f32x4 acc[4] = {};
  const short* ap = A + (long)l15 * lda + lg * 8;

  #pragma unroll 2
  for (int kb = k0; kb < k1; kb += 32){
    const float* wrow;
    int kk;
    if (kb < K1){ wrow = W1 + (long)(nb + l15) * sW1; kk = kb; }
    else        { wrow = W2 + (long)(nb + l15) * sW2; kk = kb - K1; }
    bf16x8 wf = ld8_bf(wrow + kk + lg * 8);
    bf16x8 a0 = *(const bf16x8*)(ap + kb);
    bf16x8 a1 = *(const bf16x8*)(ap + 16*lda + kb);
    bf16x8 a2 = *(const bf16x8*)(ap + 32*lda + kb);
    bf16x8 a3 = *(const bf16x8*)(ap + 48*lda + kb);
    acc[0] = __builtin_amdgcn_mfma_f32_16x16x32_bf16(a0, wf, acc[0], 0,0,0);
    acc[1] = __builtin_amdgcn_mfma_f32_16x16x32_bf16(a1, wf, acc[1], 0,0,0);
    acc[2] = __builtin_amdgcn_mfma_f32_16x16x32_bf16(a2, wf, acc[2], 0,0,0);
    acc[3] = __builtin_amdgcn_mfma_f32_16x16x32_bf16(a3, wf, acc[3], 0,0,0);
  }

  float* p = P + (long)blockIdx.y * 64 * N;
  #pragma unroll
  for (int mt = 0; mt < 4; ++mt){
    #pragma unroll
    for (int r = 0; r < 4; ++r){
      int m = mt*16 + lg*4 + r;
      p[(long)m * N + nb + l15] = acc[mt][r];
    }
  }
}

// C[m][n] = sum_s P[s][m][n] + bias[n]   (in-place safe when P==C, KS==1)
__global__ __launch_bounds__(256) void reduce_k(
    const float* __restrict__ P, int KS, const float* __restrict__ bias,
    float* __restrict__ C, int N)
{
  const int n = blockIdx.x * 256 + threadIdx.x;
  const int m = blockIdx.y;
  const long sl = (long)64 * N;
  float s = bias[n];
  const float* p = P + (long)m * N + n;
  for (int k = 0; k < KS; ++k) s += p[k * sl];
  C[(long)m * N + n] = s;
}

// ---------------------------------------------------------------------------
// energy: T = enc[8192,1024] @ Wbf[512,1024]^T ; scores[m] += v.tanh(T+hproj)
// grid 1024: m3 = bx&127 (fast -> XCD id), n3 = bx>>7  => all 8 n-blocks of an
// m-block land on the same XCD -> enc rows are L2 hits on re-read.
// ---------------------------------------------------------------------------
__global__ __launch_bounds__(256) void energy_k(
    const float* __restrict__ enc, const short* __restrict__ Wbf,
    const float* __restrict__ hproj, const float* __restrict__ v_w,
    float* __restrict__ scores)
{
  const int bx = blockIdx.x;
  const int m3 = bx & 127, n3 = bx >> 7;
  const int wave = threadIdx.x >> 6;
  const int lane = threadIdx.x & 63;
  const int l15  = lane & 15;
  const int lg   = lane >> 4;
  const int mb   = m3 * 64;
  const int nb   = n3 * 64 + wave * 16;

  f32x4 acc[4] = {};
  const float* ap = enc + (long)(mb + l15) * 1024 + lg * 8;
  const short* wp = Wbf + (long)(nb + l15) * 1024 + lg * 8;

  #pragma unroll 2
  for (int kb = 0; kb < 1024; kb += 32){
    bf16x8 wf = *(const bf16x8*)(wp + kb);
    bf16x8 a0 = ld8_bf(ap + kb);
    bf16x8 a1 = ld8_bf(ap + 16*1024 + kb);
    bf16x8 a2 = ld8_bf(ap + 32*1024 + kb);
    bf16x8 a3 = ld8_bf(ap + 48*1024 + kb);
    acc[0] = __builtin_amdgcn_mfma_f32_16x16x32_bf16(a0, wf, acc[0], 0,0,0);
    acc[1] = __builtin_amdgcn_mfma_f32_16x16x32_bf16(a1, wf, acc[1], 0,0,0);
    acc[2] = __builtin_amdgcn_mfma_f32_16x16x32_bf16(a2, wf, acc[2], 0,0,0);
    acc[3] = __builtin_amdgcn_mfma_f32_16x16x32_bf16(a3, wf, acc[3], 0,0,0);
  }

  const float vn = v_w[nb + l15];
  #pragma unroll
  for (int mt = 0; mt < 4; ++mt){
    #pragma unroll
    for (int r = 0; r < 4; ++r){
      int m = mb + mt*16 + lg*4 + r;
      int b = m >> 7;
      float e = fast_tanh(acc[mt][r] + hproj[(long)b*512 + nb + l15]) * vn;
      e += __shfl_xor(e, 1, 16);
      e += __shfl_xor(e, 2, 16);
      e += __shfl_xor(e, 4, 16);
      e += __shfl_xor(e, 8, 16);
      if (l15 == 0) atomicAdd(&scores[m], e);
    }
  }
}

// masked softmax over S=128 per batch row
__global__ __launch_bounds__(128) void softmax_k(
    const float* __restrict__ scores, const int* __restrict__ mask,
    float* __restrict__ aw)
{
  const int b = blockIdx.x;
  const int s = threadIdx.x;
  float v = scores[b*128 + s];
  if (mask[b*128 + s] == 0) v = -1e10f;
  __shared__ float red[128];
  red[s] = v; __syncthreads();
  for (int d = 64; d > 0; d >>= 1){
    if (s < d) red[s] = fmaxf(red[s], red[s + d]);
    __syncthreads();
  }
  float mx = red[0];
  __syncthreads();
  float e = __expf(v - mx);
  red[s] = e; __syncthreads();
  for (int d = 64; d > 0; d >>= 1){
    if (s < d) red[s] += red[s + d];
    __syncthreads();
  }
  aw[b*128 + s] = e / red[0];
}

// context -> bf16 into A0[:,512:1536] and Z[:,1024:2048]
__global__ __launch_bounds__(256) void context_k(
    const float* __restrict__ aw, const float* __restrict__ enc,
    short* __restrict__ A0, short* __restrict__ Z)
{
  const int b  = blockIdx.x;
  const int dd = blockIdx.y * 256 + threadIdx.x;   // 0..1023
  __shared__ float w[128];
  if (threadIdx.x < 128) w[threadIdx.x] = aw[b*128 + threadIdx.x];
  __syncthreads();
  float s = 0.f;
  const float* e = enc + (long)b * 131072 + dd;
  #pragma unroll 4
  for (int si = 0; si < 128; ++si) s += w[si] * e[si * 1024];
  short v = f2bf(s);
  A0[b*2560 + 512 + dd] = v;
  Z [b*2560 + 1024 + dd] = v;
}

// embedding gather -> bf16 into A0[:,0:512] and Z[:,2048:2560]
__global__ __launch_bounds__(256) void prep_k(
    const int* __restrict__ tok, const float* __restrict__ emb,
    short* __restrict__ A0, short* __restrict__ Z)
{
  const int i = blockIdx.x * 256 + threadIdx.x;   // 64*512
  const int b = i >> 9, e = i & 511;
  short v = f2bf(emb[(long)tok[b] * 512 + e]);
  A0[b*2560 + e] = v;
  Z [b*2560 + 2048 + e] = v;
}

// hidden[0] -> A0[:,1536:2560], hidden[1] -> A1[:,1024:2048]  (bf16)
__global__ __launch_bounds__(256) void hcvt_k(
    const float* __restrict__ h0, const float* __restrict__ h1,
    short* __restrict__ A0, short* __restrict__ A1)
{
  const int i = blockIdx.x * 256 + threadIdx.x;   // 64*1024
  const int b = i >> 10, n = i & 1023;
  A0[b*2560 + 1536 + n] = f2bf(h0[i]);
  A1[b*2048 + 1024 + n] = f2bf(h1[i]);
}

// attn_w[:,1024:2048] -> bf16
__global__ __launch_bounds__(256) void wcvt_k(
    const float* __restrict__ attn_w, short* __restrict__ Wbf)
{
  const int i = blockIdx.x * 256 + threadIdx.x;   // 512*1024
  const int r = i >> 10, c = i & 1023;
  Wbf[i] = f2bf(attn_w[(long)r*2048 + 1024 + c]);
}

// LSTM epilogue, fused split-K reduce: gates[b][c] = sum_s P[s][b][c] + biases
__global__ __launch_bounds__(256) void lstm_k(
    const float* __restrict__ P, int KS,
    const float* __restrict__ bi, const float* __restrict__ bh,
    const float* __restrict__ c_prev,
    float* __restrict__ h_out, float* __restrict__ c_out,
    short* __restrict__ h_bf, int bf_stride)
{
  const int i = blockIdx.x * 256 + threadIdx.x;   // 64*1024
  const int b = i >> 10, n = i & 1023;
  float g4[4];
  #pragma unroll
  for (int gi = 0; gi < 4; ++gi){
    int col = gi*1024 + n;
    float s = bi[col] + bh[col];
    const float* p = P + (long)b*4096 + col;
    for (int sl = 0; sl < KS; ++sl) s += p[(long)sl * 262144];
    g4[gi] = s;
  }
  float iv = fast_sig (g4[0]);
  float fv = fast_sig (g4[1]);
  float gv = fast_tanh(g4[2]);
  float ov = fast_sig (g4[3]);
  float c = fv * c_prev[i] + iv * gv;
  float h = ov * fast_tanh(c);
  c_out[i] = c;
  h_out[i] = h;
  h_bf[(long)b * bf_stride + n] = f2bf(h);
}

extern "C" void kernel_launch(void* const* d_in, const int* in_sizes, int n_in,
                              void* d_out, int out_size, void* d_ws, size_t ws_size,
                              hipStream_t stream)
{
  const int*   tok    = (const int*)  d_in[0];
  const float* hidden = (const float*)d_in[1];
  const float* cell   = (const float*)d_in[2];
  const float* enc    = (const float*)d_in[3];
  const int*   mask   = (const int*)  d_in[4];
  const float* emb    = (const float*)d_in[5];
  const float* attn_w = (const float*)d_in[6];
  const float* attn_b = (const float*)d_in[7];
  const float* v_w    = (const float*)d_in[8];
  const float* w_ih0  = (const float*)d_in[9];
  const float* w_hh0  = (const float*)d_in[10];
  const float* b_ih0  = (const float*)d_in[11];
  const float* b_hh0  = (const float*)d_in[12];
  const float* w_ih1  = (const float*)d_in[13];
  const float* w_hh1  = (const float*)d_in[14];
  const float* b_ih1  = (const float*)d_in[15];
  const float* b_hh1  = (const float*)d_in[16];
  const float* fc_w   = (const float*)d_in[17];
  const float* fc_b   = (const float*)d_in[18];

  float* out  = (float*)d_out;
  float* pred = out;                 // [64,32000]
  float* nh   = out + 2048000;       // [2,64,1024]
  float* nc   = out + 2179072;       // [2,64,1024]
  float* aw   = out + 2310144;       // [64,128]

  char*  wsb = (char*)d_ws;
  short* Wbf = (short*)(wsb + 0);         // 512*1024*2   = 1,048,576
  short* A0  = (short*)(wsb + 1048576);   // 64*2560*2    =   327,680
  short* A1  = (short*)(wsb + 1376256);   // 64*2048*2    =   262,144
  short* Zb  = (short*)(wsb + 1638400);   // 64*2560*2    =   327,680
  float* hpr = (float*)(wsb + 1966080);   // 64*512*4     =   131,072
  float* sco = (float*)(wsb + 2097152);   // 8192*4       =    32,768
  float* Pb  = (float*)(wsb + 2129920);   // split-K partials (shared)

  size_t avail = ws_size > 2129920 ? ws_size - 2129920 : 0;
  int KSf = avail >= 32768000ul ? 4 : avail >= 16384000ul ? 2 :
            avail >=  8192000ul ? 1 : 0;          // 0 -> direct to pred
  int KSg = avail >= 16777216ul ? 16 : avail >= 8388608ul ? 8 :
            avail >=  4194304ul ? 4 : 1;
  int KSh = avail >=  1048576ul ? 8 : 1;

  wcvt_k<<<2048, 256, 0, stream>>>(attn_w, Wbf);
  prep_k<<<128, 256, 0, stream>>>(tok, emb, A0, Zb);
  hcvt_k<<<256, 256, 0, stream>>>(hidden, hidden + 65536, A0, A1);

  // hproj = h_top @ attn_w[:,0:1024]^T + attn_b
  float* PH = (KSh > 1) ? Pb : hpr;
  gemm_ws<<<dim3(8, KSh), 256, 0, stream>>>(A1 + 1024, 2048,
                                            attn_w, 2048, 1024, nullptr, 0,
                                            1024 / KSh, PH, 512);
  reduce_k<<<dim3(2, 64), 256, 0, stream>>>(PH, KSh, attn_b, hpr, 512);

  hipMemsetAsync(sco, 0, 32768, stream);
  energy_k<<<1024, 256, 0, stream>>>(enc, Wbf, hpr, v_w, sco);
  softmax_k<<<64, 128, 0, stream>>>(sco, mask, aw);
  context_k<<<dim3(64, 4), 256, 0, stream>>>(aw, enc, A0, Zb);

  // layer 0: A0 = [emb | ctx | h0_prev], W = [w_ih0 | w_hh0]
  gemm_ws<<<dim3(64, KSg), 256, 0, stream>>>(A0, 2560,
                                             w_ih0, 1536, 1536, w_hh0, 1024,
                                             2560 / KSg, Pb, 4096);
  lstm_k<<<256, 256, 0, stream>>>(Pb, KSg, b_ih0, b_hh0, cell,
                                  nh, nc, A1, 2048);

  // layer 1: A1 = [h0' | h1_prev], W = [w_ih1 | w_hh1]
  gemm_ws<<<dim3(64, KSg), 256, 0, stream>>>(A1, 2048,
                                             w_ih1, 1024, 1024, w_hh1, 1024,
                                             2048 / KSg, Pb, 4096);
  lstm_k<<<256, 256, 0, stream>>>(Pb, KSg, b_ih1, b_hh1, cell + 65536,
                                  nh + 65536, nc + 65536, Zb, 2560);

  // prediction = Zb @ fc_w^T + fc_b
  float* PF = (KSf >= 1) ? Pb : pred;
  int ksf = (KSf >= 1) ? KSf : 1;
  gemm_ws<<<dim3(500, ksf), 256, 0, stream>>>(Zb, 2560,
                                              fc_w, 2560, 2560, nullptr, 0,
                                              2560 / ksf, PF, 32000);
  reduce_k<<<dim3(125, 64), 256, 0, stream>>>(PF, ksf, fc_b, pred, 32000);
}

// Round 3
// 364.274 us; speedup vs baseline: 2.0273x; 1.0943x over previous
//
#include <hip/hip_runtime.h>

// Decoder step: embed -> additive attention -> 2-layer LSTM -> fc
// B=64, S=128, E=512, H=512, H2=1024, V=32000
// GEMMs: bf16 MFMA 16x16x32. enc/attn_w/activations pre-packed bf16;
// LSTM + fc weights cvt'd f32->bf16 in-register while streaming.
// Split-K via gridDim.y into ws partials; consumers fuse reduction + bias.

typedef __attribute__((ext_vector_type(8))) short bf16x8;
typedef __attribute__((ext_vector_type(4))) float f32x4;

__device__ __forceinline__ short f2bf(float f){
  __bf16 h = (__bf16)f;
  return __builtin_bit_cast(short, h);
}

__device__ __forceinline__ bf16x8 ld8_bf(const float* __restrict__ p){
  float4 v0 = *(const float4*)p;
  float4 v1 = *(const float4*)(p + 4);
  bf16x8 r;
  r[0]=f2bf(v0.x); r[1]=f2bf(v0.y); r[2]=f2bf(v0.z); r[3]=f2bf(v0.w);
  r[4]=f2bf(v1.x); r[5]=f2bf(v1.y); r[6]=f2bf(v1.z); r[7]=f2bf(v1.w);
  return r;
}

__device__ __forceinline__ float fast_tanh(float x){
  x = fminf(fmaxf(x, -15.f), 15.f);
  float t = __expf(2.f * x);
  return (t - 1.f) / (t + 1.f);
}
__device__ __forceinline__ float fast_sig(float x){
  return 1.f / (1.f + __expf(-x));
}

// ---------------------------------------------------------------------------
// Fused prep: enc->bf16, attn_w[:,1024:2048]->bf16, emb gather, hidden cvt,
// scores zero. Block ranges: [0,4096) enc, [4096,4352) attn_w, [4352,4368)
// emb, [4368,4400) hidden, [4400,4404) scores.
// ---------------------------------------------------------------------------
__global__ __launch_bounds__(256) void prep_all(
    const int* __restrict__ tok, const float* __restrict__ emb,
    const float* __restrict__ hidden, const float* __restrict__ enc,
    const float* __restrict__ attn_w,
    short* __restrict__ encbf, short* __restrict__ Wbf,
    short* __restrict__ A0, short* __restrict__ A1, short* __restrict__ Zb,
    float* __restrict__ sco)
{
  const int bid = blockIdx.x, t = threadIdx.x;
  if (bid < 4096){
    long i = ((long)bid*256 + t)*8;
    *(bf16x8*)(encbf + i) = ld8_bf(enc + i);
  } else if (bid < 4352){
    int j = (bid-4096)*256 + t;
    int r = j >> 7, c = (j & 127)*8;
    *(bf16x8*)(Wbf + r*1024 + c) = ld8_bf(attn_w + (long)r*2048 + 1024 + c);
  } else if (bid < 4368){
    int j = (bid-4352)*256 + t;
    int b = j >> 6, e8 = (j & 63)*8;
    bf16x8 v = ld8_bf(emb + (long)tok[b]*512 + e8);
    *(bf16x8*)(A0 + b*2560 + e8) = v;
    *(bf16x8*)(Zb + b*2560 + 2048 + e8) = v;
  } else if (bid < 4400){
    int j = (bid-4368)*256 + t;
    int b = j >> 7, n8 = (j & 127)*8;
    *(bf16x8*)(A0 + b*2560 + 1536 + n8) = ld8_bf(hidden + (long)b*1024 + n8);
    *(bf16x8*)(A1 + b*2048 + 1024 + n8) = ld8_bf(hidden + 65536 + (long)b*1024 + n8);
  } else {
    int j = (bid-4400)*256 + t;           // 0..1023, 8 floats each
    float4 z = {0.f, 0.f, 0.f, 0.f};
    *(float4*)(sco + j*8) = z;
    *(float4*)(sco + j*8 + 4) = z;
  }
}

// ---------------------------------------------------------------------------
// P[by][64][N] = A_bf16[64,K] @ [W1|W2][N,:]^T restricted to k-slice by.
// One wave -> 64m x 16n tile; block = 4 waves = 64 cols.
// ---------------------------------------------------------------------------
__global__ __launch_bounds__(256) void gemm_ws(
    const short* __restrict__ A, int lda,
    const float* __restrict__ W1, int sW1, int K1,
    const float* __restrict__ W2, int sW2,
    int Kslice, float* __restrict__ P, int N)
{
  const int wave = threadIdx.x >> 6;
  const int lane = threadIdx.x & 63;
  const int l15  = lane & 15;
  const int lg   = lane >> 4;
  const int nb   = blockIdx.x * 64 + wave * 16;
  const int k0   = blockIdx.y * Kslice;
  const int k1   = k0 + Kslice;

  f32x4 acc[4] = {};
  const short* ap = A + (long)l15 * lda + lg * 8;

  #pragma unroll 2
  for (int kb = k0; kb < k1; kb += 32){
    const float* wrow;
    int kk;
    if (kb < K1){ wrow = W1 + (long)(nb + l15) * sW1; kk = kb; }
    else        { wrow = W2 + (long)(nb + l15) * sW2; kk = kb - K1; }
    bf16x8 wf = ld8_bf(wrow + kk + lg * 8);
    bf16x8 a0 = *(const bf16x8*)(ap + kb);
    bf16x8 a1 = *(const bf16x8*)(ap + 16*lda + kb);
    bf16x8 a2 = *(const bf16x8*)(ap + 32*lda + kb);
    bf16x8 a3 = *(const bf16x8*)(ap + 48*lda + kb);
    acc[0] = __builtin_amdgcn_mfma_f32_16x16x32_bf16(a0, wf, acc[0], 0,0,0);
    acc[1] = __builtin_amdgcn_mfma_f32_16x16x32_bf16(a1, wf, acc[1], 0,0,0);
    acc[2] = __builtin_amdgcn_mfma_f32_16x16x32_bf16(a2, wf, acc[2], 0,0,0);
    acc[3] = __builtin_amdgcn_mfma_f32_16x16x32_bf16(a3, wf, acc[3], 0,0,0);
  }

  float* p = P + (long)blockIdx.y * 64 * N;
  #pragma unroll
  for (int mt = 0; mt < 4; ++mt){
    #pragma unroll
    for (int r = 0; r < 4; ++r){
      int m = mt*16 + lg*4 + r;
      p[(long)m * N + nb + l15] = acc[mt][r];
    }
  }
}

// C[m][n] = sum_s P[s][m][n] + bias[n]   (float4)
__global__ __launch_bounds__(256) void reduce_k(
    const float* __restrict__ P, int KS, const float* __restrict__ bias,
    float* __restrict__ C, int N)
{
  const int n4 = (blockIdx.x * 256 + threadIdx.x) * 4;
  if (n4 >= N) return;
  const int m = blockIdx.y;
  const long sl = (long)64 * N;
  float4 s = *(const float4*)(bias + n4);
  const float* p = P + (long)m * N + n4;
  for (int k = 0; k < KS; ++k){
    float4 v = *(const float4*)(p + k * sl);
    s.x += v.x; s.y += v.y; s.z += v.z; s.w += v.w;
  }
  *(float4*)(C + (long)m * N + n4) = s;
}

// ---------------------------------------------------------------------------
// energy: hproj inline (f32 dot over attn_w[:,0:1024]) + T = encbf @ Wbf^T,
// scores[m] += v . tanh(T + hproj).  grid 1024: m3 = bx&127 (fast -> XCD id).
// ---------------------------------------------------------------------------
__global__ __launch_bounds__(256) void energy_k(
    const short* __restrict__ encbf, const short* __restrict__ Wbf,
    const float* __restrict__ hidden_top, const float* __restrict__ attn_w,
    const float* __restrict__ attn_b, const float* __restrict__ v_w,
    float* __restrict__ scores)
{
  const int bx = blockIdx.x;
  const int m3 = bx & 127, n3 = bx >> 7;
  const int wave = threadIdx.x >> 6;
  const int lane = threadIdx.x & 63;
  const int l15  = lane & 15;
  const int lg   = lane >> 4;
  const int mb   = m3 * 64;
  const int nb   = n3 * 64 + wave * 16;
  const int b    = mb >> 7;

  // hproj[b][nb+l15]: K=1024 dot, split over lg (4 x 256) + shuffle reduce
  const float4* hv = (const float4*)(hidden_top + (long)b*1024 + lg*256);
  const float4* wv = (const float4*)(attn_w + (long)(nb + l15)*2048 + lg*256);
  float hp = 0.f;
  #pragma unroll 8
  for (int k = 0; k < 64; ++k){
    float4 a = hv[k], w = wv[k];
    hp += a.x*w.x + a.y*w.y + a.z*w.z + a.w*w.w;
  }
  hp += __shfl_xor(hp, 16);
  hp += __shfl_xor(hp, 32);
  hp += attn_b[nb + l15];

  f32x4 acc[4] = {};
  const short* ap = encbf + (long)(mb + l15) * 1024 + lg * 8;
  const short* wp = Wbf   + (long)(nb + l15) * 1024 + lg * 8;

  #pragma unroll 2
  for (int kb = 0; kb < 1024; kb += 32){
    bf16x8 wf = *(const bf16x8*)(wp + kb);
    bf16x8 a0 = *(const bf16x8*)(ap + kb);
    bf16x8 a1 = *(const bf16x8*)(ap + 16*1024 + kb);
    bf16x8 a2 = *(const bf16x8*)(ap + 32*1024 + kb);
    bf16x8 a3 = *(const bf16x8*)(ap + 48*1024 + kb);
    acc[0] = __builtin_amdgcn_mfma_f32_16x16x32_bf16(a0, wf, acc[0], 0,0,0);
    acc[1] = __builtin_amdgcn_mfma_f32_16x16x32_bf16(a1, wf, acc[1], 0,0,0);
    acc[2] = __builtin_amdgcn_mfma_f32_16x16x32_bf16(a2, wf, acc[2], 0,0,0);
    acc[3] = __builtin_amdgcn_mfma_f32_16x16x32_bf16(a3, wf, acc[3], 0,0,0);
  }

  const float vn = v_w[nb + l15];
  #pragma unroll
  for (int mt = 0; mt < 4; ++mt){
    #pragma unroll
    for (int r = 0; r < 4; ++r){
      int m = mb + mt*16 + lg*4 + r;
      float e = fast_tanh(acc[mt][r] + hp) * vn;
      e += __shfl_xor(e, 1, 16);
      e += __shfl_xor(e, 2, 16);
      e += __shfl_xor(e, 4, 16);
      e += __shfl_xor(e, 8, 16);
      if (l15 == 0) atomicAdd(&scores[m], e);
    }
  }
}

// ---------------------------------------------------------------------------
// Fused masked softmax + context: each block (b, dchunk) redoes the cheap
// 128-wide softmax, then computes its 256 context dims from bf16 enc.
// ---------------------------------------------------------------------------
__global__ __launch_bounds__(256) void ctxsm_k(
    const float* __restrict__ sco, const int* __restrict__ mask,
    const short* __restrict__ encbf, float* __restrict__ aw,
    short* __restrict__ A0, short* __restrict__ Zb)
{
  const int bb = blockIdx.x;
  const int t  = threadIdx.x;
  __shared__ float red[128];
  __shared__ float w[128];
  float v = 0.f;
  if (t < 128){
    v = sco[bb*128 + t];
    if (mask[bb*128 + t] == 0) v = -1e10f;
    red[t] = v;
  }
  __syncthreads();
  for (int d = 64; d > 0; d >>= 1){
    if (t < d) red[t] = fmaxf(red[t], red[t + d]);
    __syncthreads();
  }
  const float mx = red[0];
  __syncthreads();
  if (t < 128){
    float e = __expf(v - mx);
    w[t] = e; red[t] = e;
  }
  __syncthreads();
  for (int d = 64; d > 0; d >>= 1){
    if (t < d) red[t] += red[t + d];
    __syncthreads();
  }
  const float inv = 1.f / red[0];
  if (blockIdx.y == 0 && t < 128) aw[bb*128 + t] = w[t] * inv;

  const int dd = blockIdx.y * 256 + t;        // 0..1023
  const unsigned short* e = (const unsigned short*)encbf + (long)bb*131072 + dd;
  float s = 0.f;
  #pragma unroll 4
  for (int si = 0; si < 128; ++si){
    float ev = __builtin_bit_cast(float, (unsigned)e[si*1024] << 16);
    s += w[si] * ev;
  }
  s *= inv;
  short vbf = f2bf(s);
  A0[bb*2560 + 512  + dd] = vbf;
  Zb[bb*2560 + 1024 + dd] = vbf;
}

// LSTM epilogue with fused split-K reduce
__global__ __launch_bounds__(256) void lstm_k(
    const float* __restrict__ P, int KS,
    const float* __restrict__ bi, const float* __restrict__ bh,
    const float* __restrict__ c_prev,
    float* __restrict__ h_out, float* __restrict__ c_out,
    short* __restrict__ h_bf, int bf_stride)
{
  const int i = blockIdx.x * 256 + threadIdx.x;   // 64*1024
  const int b = i >> 10, n = i & 1023;
  float g4[4];
  #pragma unroll
  for (int gi = 0; gi < 4; ++gi){
    int col = gi*1024 + n;
    float s = bi[col] + bh[col];
    const float* p = P + (long)b*4096 + col;
    for (int sl = 0; sl < KS; ++sl) s += p[(long)sl * 262144];
    g4[gi] = s;
  }
  float iv = fast_sig (g4[0]);
  float fv = fast_sig (g4[1]);
  float gv = fast_tanh(g4[2]);
  float ov = fast_sig (g4[3]);
  float c = fv * c_prev[i] + iv * gv;
  float h = ov * fast_tanh(c);
  c_out[i] = c;
  h_out[i] = h;
  h_bf[(long)b * bf_stride + n] = f2bf(h);
}

extern "C" void kernel_launch(void* const* d_in, const int* in_sizes, int n_in,
                              void* d_out, int out_size, void* d_ws, size_t ws_size,
                              hipStream_t stream)
{
  const int*   tok    = (const int*)  d_in[0];
  const float* hidden = (const float*)d_in[1];
  const float* cell   = (const float*)d_in[2];
  const float* enc    = (const float*)d_in[3];
  const int*   mask   = (const int*)  d_in[4];
  const float* emb    = (const float*)d_in[5];
  const float* attn_w = (const float*)d_in[6];
  const float* attn_b = (const float*)d_in[7];
  const float* v_w    = (const float*)d_in[8];
  const float* w_ih0  = (const float*)d_in[9];
  const float* w_hh0  = (const float*)d_in[10];
  const float* b_ih0  = (const float*)d_in[11];
  const float* b_hh0  = (const float*)d_in[12];
  const float* w_ih1  = (const float*)d_in[13];
  const float* w_hh1  = (const float*)d_in[14];
  const float* b_ih1  = (const float*)d_in[15];
  const float* b_hh1  = (const float*)d_in[16];
  const float* fc_w   = (const float*)d_in[17];
  const float* fc_b   = (const float*)d_in[18];

  float* out  = (float*)d_out;
  float* pred = out;                 // [64,32000]
  float* nh   = out + 2048000;       // [2,64,1024]
  float* nc   = out + 2179072;       // [2,64,1024]
  float* aw   = out + 2310144;       // [64,128]

  char*  wsb   = (char*)d_ws;
  short* encbf = (short*)(wsb + 0);          // 8,388,608 bf16 = 16,777,216 B
  short* Wbf   = (short*)(wsb + 16777216);   // 512*1024*2  = 1,048,576 B
  short* A0    = (short*)(wsb + 17825792);   // 64*2560*2   =   327,680 B
  short* A1    = (short*)(wsb + 18153472);   // 64*2048*2   =   262,144 B
  short* Zb    = (short*)(wsb + 18415616);   // 64*2560*2   =   327,680 B
  float* sco   = (float*)(wsb + 18743296);   // 8192*4      =    32,768 B
  float* Pb    = (float*)(wsb + 18776064);   // split-K partials

  size_t avail = ws_size > 18776064 ? ws_size - 18776064 : 0;
  int KSf = avail >= 32768000ul ? 4 : avail >= 16384000ul ? 2 : 1;
  int KSg = avail >= 16777216ul ? 16 : avail >= 8388608ul ? 8 : 4;

  prep_all<<<4404, 256, 0, stream>>>(tok, emb, hidden, enc, attn_w,
                                     encbf, Wbf, A0, A1, Zb, sco);

  energy_k<<<1024, 256, 0, stream>>>(encbf, Wbf, hidden + 65536,
                                     attn_w, attn_b, v_w, sco);

  ctxsm_k<<<dim3(64, 4), 256, 0, stream>>>(sco, mask, encbf, aw, A0, Zb);

  // layer 0: A0 = [emb | ctx | h0_prev], W = [w_ih0 | w_hh0]
  gemm_ws<<<dim3(64, KSg), 256, 0, stream>>>(A0, 2560,
                                             w_ih0, 1536, 1536, w_hh0, 1024,
                                             2560 / KSg, Pb, 4096);
  lstm_k<<<256, 256, 0, stream>>>(Pb, KSg, b_ih0, b_hh0, cell,
                                  nh, nc, A1, 2048);

  // layer 1: A1 = [h0' | h1_prev], W = [w_ih1 | w_hh1]
  gemm_ws<<<dim3(64, KSg), 256, 0, stream>>>(A1, 2048,
                                             w_ih1, 1024, 1024, w_hh1, 1024,
                                             2048 / KSg, Pb, 4096);
  lstm_k<<<256, 256, 0, stream>>>(Pb, KSg, b_ih1, b_hh1, cell + 65536,
                                  nh + 65536, nc + 65536, Zb, 2560);

  // prediction = Zb @ fc_w^T + fc_b
  gemm_ws<<<dim3(500, KSf), 256, 0, stream>>>(Zb, 2560,
                                              fc_w, 2560, 2560, nullptr, 0,
                                              2560 / KSf, Pb, 32000);
  reduce_k<<<dim3(32, 64), 256, 0, stream>>>(Pb, KSf, fc_b, pred, 32000);
}

// Round 4
// 333.957 us; speedup vs baseline: 2.2113x; 1.0908x over previous
//
#include <hip/hip_runtime.h>

// Decoder step: embed -> additive attention -> 2-layer LSTM -> fc
// B=64, S=128, E=512, H=512, H2=1024, V=32000
// Streaming GEMMs: bf16 MFMA 16x16x32, explicit 1-ahead register prefetch
// (raw f32 loads, cvt at use) so W loads pipeline across k-iterations.

typedef __attribute__((ext_vector_type(8))) short bf16x8;
typedef __attribute__((ext_vector_type(4))) float f32x4;

__device__ __forceinline__ short f2bf(float f){
  __bf16 h = (__bf16)f;
  return __builtin_bit_cast(short, h);
}

__device__ __forceinline__ bf16x8 cvt8(float4 a, float4 b){
  bf16x8 r;
  r[0]=f2bf(a.x); r[1]=f2bf(a.y); r[2]=f2bf(a.z); r[3]=f2bf(a.w);
  r[4]=f2bf(b.x); r[5]=f2bf(b.y); r[6]=f2bf(b.z); r[7]=f2bf(b.w);
  return r;
}

__device__ __forceinline__ bf16x8 ld8_bf(const float* __restrict__ p){
  return cvt8(*(const float4*)p, *(const float4*)(p + 4));
}

__device__ __forceinline__ float fast_tanh(float x){
  x = fminf(fmaxf(x, -15.f), 15.f);
  float t = __expf(2.f * x);
  return (t - 1.f) / (t + 1.f);
}
__device__ __forceinline__ float fast_sig(float x){
  return 1.f / (1.f + __expf(-x));
}

// ---------------------------------------------------------------------------
// Fused prep: enc->bf16, attn_w[:,1024:2048]->bf16, emb gather, hidden cvt,
// scores zero.
// ---------------------------------------------------------------------------
__global__ __launch_bounds__(256) void prep_all(
    const int* __restrict__ tok, const float* __restrict__ emb,
    const float* __restrict__ hidden, const float* __restrict__ enc,
    const float* __restrict__ attn_w,
    short* __restrict__ encbf, short* __restrict__ Wbf,
    short* __restrict__ A0, short* __restrict__ A1, short* __restrict__ Zb,
    float* __restrict__ sco)
{
  const int bid = blockIdx.x, t = threadIdx.x;
  if (bid < 4096){
    long i = ((long)bid*256 + t)*8;
    *(bf16x8*)(encbf + i) = ld8_bf(enc + i);
  } else if (bid < 4352){
    int j = (bid-4096)*256 + t;
    int r = j >> 7, c = (j & 127)*8;
    *(bf16x8*)(Wbf + r*1024 + c) = ld8_bf(attn_w + (long)r*2048 + 1024 + c);
  } else if (bid < 4368){
    int j = (bid-4352)*256 + t;
    int b = j >> 6, e8 = (j & 63)*8;
    bf16x8 v = ld8_bf(emb + (long)tok[b]*512 + e8);
    *(bf16x8*)(A0 + b*2560 + e8) = v;
    *(bf16x8*)(Zb + b*2560 + 2048 + e8) = v;
  } else if (bid < 4400){
    int j = (bid-4368)*256 + t;
    int b = j >> 7, n8 = (j & 127)*8;
    *(bf16x8*)(A0 + b*2560 + 1536 + n8) = ld8_bf(hidden + (long)b*1024 + n8);
    *(bf16x8*)(A1 + b*2048 + 1024 + n8) = ld8_bf(hidden + 65536 + (long)b*1024 + n8);
  } else {
    int j = (bid-4400)*256 + t;
    float4 z = {0.f, 0.f, 0.f, 0.f};
    *(float4*)(sco + j*8) = z;
    *(float4*)(sco + j*8 + 4) = z;
  }
}

// ---------------------------------------------------------------------------
// P[by][64][N] = A_bf16[64,K] @ [W1|W2][N,:]^T on k-slice by, pipelined.
// Wave: NT n-tiles of 16 cols x 64 rows of A. Block: 4 waves = 64*NT cols.
// Requires Kslice % 32 == 0 and (for two segments) Kslice | K1.
// ---------------------------------------------------------------------------
template<int NT>
__global__ __launch_bounds__(256) void gemm2(
    const short* __restrict__ A, int lda,
    const float* __restrict__ W1, int sW1, int K1,
    const float* __restrict__ W2, int sW2,
    int Kslice, float* __restrict__ P, int N)
{
  const int wave = threadIdx.x >> 6;
  const int lane = threadIdx.x & 63;
  const int l15  = lane & 15;
  const int lg   = lane >> 4;
  const int nb   = (blockIdx.x * 4 + wave) * (16*NT);
  const int k0   = blockIdx.y * Kslice;

  const float* W; int sW, koff;
  if (k0 < K1){ W = W1; sW = sW1; koff = k0; }
  else        { W = W2; sW = sW2; koff = k0 - K1; }

  const short* ap = A + (long)l15 * lda + k0 + lg*8;
  const float* wp = W + (long)(nb + l15) * sW + koff + lg*8;

  f32x4 acc[NT][4];
  #pragma unroll
  for (int t = 0; t < NT; ++t)
    #pragma unroll
    for (int m = 0; m < 4; ++m) acc[t][m] = (f32x4){0.f,0.f,0.f,0.f};

  float4 w0[NT], w1[NT];
  bf16x8 ar[4];
  #pragma unroll
  for (int t = 0; t < NT; ++t){
    w0[t] = *(const float4*)(wp + (long)t*16*sW);
    w1[t] = *(const float4*)(wp + (long)t*16*sW + 4);
  }
  #pragma unroll
  for (int m = 0; m < 4; ++m) ar[m] = *(const bf16x8*)(ap + m*16*lda);

  for (int kb = 32; kb < Kslice; kb += 32){
    float4 cw0[NT], cw1[NT]; bf16x8 ca[4];
    #pragma unroll
    for (int t = 0; t < NT; ++t){ cw0[t] = w0[t]; cw1[t] = w1[t]; }
    #pragma unroll
    for (int m = 0; m < 4; ++m) ca[m] = ar[m];
    // issue next iteration's loads before consuming current
    #pragma unroll
    for (int t = 0; t < NT; ++t){
      w0[t] = *(const float4*)(wp + kb + (long)t*16*sW);
      w1[t] = *(const float4*)(wp + kb + (long)t*16*sW + 4);
    }
    #pragma unroll
    for (int m = 0; m < 4; ++m) ar[m] = *(const bf16x8*)(ap + kb + m*16*lda);
    #pragma unroll
    for (int t = 0; t < NT; ++t){
      bf16x8 wf = cvt8(cw0[t], cw1[t]);
      #pragma unroll
      for (int m = 0; m < 4; ++m)
        acc[t][m] = __builtin_amdgcn_mfma_f32_16x16x32_bf16(ca[m], wf, acc[t][m], 0,0,0);
    }
  }
  #pragma unroll
  for (int t = 0; t < NT; ++t){
    bf16x8 wf = cvt8(w0[t], w1[t]);
    #pragma unroll
    for (int m = 0; m < 4; ++m)
      acc[t][m] = __builtin_amdgcn_mfma_f32_16x16x32_bf16(ar[m], wf, acc[t][m], 0,0,0);
  }

  float* p = P + (long)blockIdx.y * 64 * N;
  #pragma unroll
  for (int t = 0; t < NT; ++t)
    #pragma unroll
    for (int mt = 0; mt < 4; ++mt)
      #pragma unroll
      for (int r = 0; r < 4; ++r){
        int m = mt*16 + lg*4 + r;
        p[(long)m * N + nb + t*16 + l15] = acc[t][mt][r];
      }
}

// C[m][n] = sum_s P[s][m][n] + bias[n]   (float4)
__global__ __launch_bounds__(256) void reduce_k(
    const float* __restrict__ P, int KS, const float* __restrict__ bias,
    float* __restrict__ C, int N)
{
  const int n4 = (blockIdx.x * 256 + threadIdx.x) * 4;
  if (n4 >= N) return;
  const int m = blockIdx.y;
  const long sl = (long)64 * N;
  float4 s = *(const float4*)(bias + n4);
  const float* p = P + (long)m * N + n4;
  for (int k = 0; k < KS; ++k){
    float4 v = *(const float4*)(p + k * sl);
    s.x += v.x; s.y += v.y; s.z += v.z; s.w += v.w;
  }
  *(float4*)(C + (long)m * N + n4) = s;
}

// ---------------------------------------------------------------------------
// energy: hproj inline + T = encbf @ Wbf^T, scores[m] += v . tanh(T + hproj)
// grid 1024: m3 = bx&127 (fast -> XCD id) for enc L2 reuse.
// ---------------------------------------------------------------------------
__global__ __launch_bounds__(256) void energy_k(
    const short* __restrict__ encbf, const short* __restrict__ Wbf,
    const float* __restrict__ hidden_top, const float* __restrict__ attn_w,
    const float* __restrict__ attn_b, const float* __restrict__ v_w,
    float* __restrict__ scores)
{
  const int bx = blockIdx.x;
  const int m3 = bx & 127, n3 = bx >> 7;
  const int wave = threadIdx.x >> 6;
  const int lane = threadIdx.x & 63;
  const int l15  = lane & 15;
  const int lg   = lane >> 4;
  const int mb   = m3 * 64;
  const int nb   = n3 * 64 + wave * 16;
  const int b    = mb >> 7;

  // hproj: K=1024 dot split over lg (4 x 256), 4 independent accumulators
  const float4* hv = (const float4*)(hidden_top + (long)b*1024 + lg*256);
  const float4* wv = (const float4*)(attn_w + (long)(nb + l15)*2048 + lg*256);
  float hs0 = 0.f, hs1 = 0.f, hs2 = 0.f, hs3 = 0.f;
  #pragma unroll 4
  for (int k = 0; k < 64; k += 4){
    float4 a0 = hv[k],   q0 = wv[k];
    float4 a1 = hv[k+1], q1 = wv[k+1];
    float4 a2 = hv[k+2], q2 = wv[k+2];
    float4 a3 = hv[k+3], q3 = wv[k+3];
    hs0 += a0.x*q0.x + a0.y*q0.y + a0.z*q0.z + a0.w*q0.w;
    hs1 += a1.x*q1.x + a1.y*q1.y + a1.z*q1.z + a1.w*q1.w;
    hs2 += a2.x*q2.x + a2.y*q2.y + a2.z*q2.z + a2.w*q2.w;
    hs3 += a3.x*q3.x + a3.y*q3.y + a3.z*q3.z + a3.w*q3.w;
  }
  float hp = (hs0 + hs1) + (hs2 + hs3);
  hp += __shfl_xor(hp, 16);
  hp += __shfl_xor(hp, 32);
  hp += attn_b[nb + l15];

  f32x4 acc[4] = {};
  const short* ap = encbf + (long)(mb + l15) * 1024 + lg * 8;
  const short* wpb = Wbf  + (long)(nb + l15) * 1024 + lg * 8;

  bf16x8 wn  = *(const bf16x8*)(wpb);
  bf16x8 an0 = *(const bf16x8*)(ap);
  bf16x8 an1 = *(const bf16x8*)(ap + 16*1024);
  bf16x8 an2 = *(const bf16x8*)(ap + 32*1024);
  bf16x8 an3 = *(const bf16x8*)(ap + 48*1024);
  for (int kb = 32; kb < 1024; kb += 32){
    bf16x8 wc = wn, c0 = an0, c1 = an1, c2 = an2, c3 = an3;
    wn  = *(const bf16x8*)(wpb + kb);
    an0 = *(const bf16x8*)(ap + kb);
    an1 = *(const bf16x8*)(ap + kb + 16*1024);
    an2 = *(const bf16x8*)(ap + kb + 32*1024);
    an3 = *(const bf16x8*)(ap + kb + 48*1024);
    acc[0] = __builtin_amdgcn_mfma_f32_16x16x32_bf16(c0, wc, acc[0], 0,0,0);
    acc[1] = __builtin_amdgcn_mfma_f32_16x16x32_bf16(c1, wc, acc[1], 0,0,0);
    acc[2] = __builtin_amdgcn_mfma_f32_16x16x32_bf16(c2, wc, acc[2], 0,0,0);
    acc[3] = __builtin_amdgcn_mfma_f32_16x16x32_bf16(c3, wc, acc[3], 0,0,0);
  }
  acc[0] = __builtin_amdgcn_mfma_f32_16x16x32_bf16(an0, wn, acc[0], 0,0,0);
  acc[1] = __builtin_amdgcn_mfma_f32_16x16x32_bf16(an1, wn, acc[1], 0,0,0);
  acc[2] = __builtin_amdgcn_mfma_f32_16x16x32_bf16(an2, wn, acc[2], 0,0,0);
  acc[3] = __builtin_amdgcn_mfma_f32_16x16x32_bf16(an3, wn, acc[3], 0,0,0);

  const float vn = v_w[nb + l15];
  #pragma unroll
  for (int mt = 0; mt < 4; ++mt){
    #pragma unroll
    for (int r = 0; r < 4; ++r){
      int m = mb + mt*16 + lg*4 + r;
      float e = fast_tanh(acc[mt][r] + hp) * vn;
      e += __shfl_xor(e, 1, 16);
      e += __shfl_xor(e, 2, 16);
      e += __shfl_xor(e, 4, 16);
      e += __shfl_xor(e, 8, 16);
      if (l15 == 0) atomicAdd(&scores[m], e);
    }
  }
}

// Fused masked softmax + context
__global__ __launch_bounds__(256) void ctxsm_k(
    const float* __restrict__ sco, const int* __restrict__ mask,
    const short* __restrict__ encbf, float* __restrict__ aw,
    short* __restrict__ A0, short* __restrict__ Zb)
{
  const int bb = blockIdx.x;
  const int t  = threadIdx.x;
  __shared__ float red[128];
  __shared__ float w[128];
  float v = 0.f;
  if (t < 128){
    v = sco[bb*128 + t];
    if (mask[bb*128 + t] == 0) v = -1e10f;
    red[t] = v;
  }
  __syncthreads();
  for (int d = 64; d > 0; d >>= 1){
    if (t < d) red[t] = fmaxf(red[t], red[t + d]);
    __syncthreads();
  }
  const float mx = red[0];
  __syncthreads();
  if (t < 128){
    float e = __expf(v - mx);
    w[t] = e; red[t] = e;
  }
  __syncthreads();
  for (int d = 64; d > 0; d >>= 1){
    if (t < d) red[t] += red[t + d];
    __syncthreads();
  }
  const float inv = 1.f / red[0];
  if (blockIdx.y == 0 && t < 128) aw[bb*128 + t] = w[t] * inv;

  const int dd = blockIdx.y * 256 + t;
  const unsigned short* e = (const unsigned short*)encbf + (long)bb*131072 + dd;
  float s = 0.f;
  #pragma unroll 4
  for (int si = 0; si < 128; ++si){
    float ev = __builtin_bit_cast(float, (unsigned)e[si*1024] << 16);
    s += w[si] * ev;
  }
  s *= inv;
  short vbf = f2bf(s);
  A0[bb*2560 + 512  + dd] = vbf;
  Zb[bb*2560 + 1024 + dd] = vbf;
}

// LSTM epilogue with fused split-K reduce
__global__ __launch_bounds__(256) void lstm_k(
    const float* __restrict__ P, int KS,
    const float* __restrict__ bi, const float* __restrict__ bh,
    const float* __restrict__ c_prev,
    float* __restrict__ h_out, float* __restrict__ c_out,
    short* __restrict__ h_bf, int bf_stride)
{
  const int i = blockIdx.x * 256 + threadIdx.x;
  const int b = i >> 10, n = i & 1023;
  float g4[4];
  #pragma unroll
  for (int gi = 0; gi < 4; ++gi){
    int col = gi*1024 + n;
    float s = bi[col] + bh[col];
    const float* p = P + (long)b*4096 + col;
    for (int sl = 0; sl < KS; ++sl) s += p[(long)sl * 262144];
    g4[gi] = s;
  }
  float iv = fast_sig (g4[0]);
  float fv = fast_sig (g4[1]);
  float gv = fast_tanh(g4[2]);
  float ov = fast_sig (g4[3]);
  float c = fv * c_prev[i] + iv * gv;
  float h = ov * fast_tanh(c);
  c_out[i] = c;
  h_out[i] = h;
  h_bf[(long)b * bf_stride + n] = f2bf(h);
}

extern "C" void kernel_launch(void* const* d_in, const int* in_sizes, int n_in,
                              void* d_out, int out_size, void* d_ws, size_t ws_size,
                              hipStream_t stream)
{
  const int*   tok    = (const int*)  d_in[0];
  const float* hidden = (const float*)d_in[1];
  const float* cell   = (const float*)d_in[2];
  const float* enc    = (const float*)d_in[3];
  const int*   mask   = (const int*)  d_in[4];
  const float* emb    = (const float*)d_in[5];
  const float* attn_w = (const float*)d_in[6];
  const float* attn_b = (const float*)d_in[7];
  const float* v_w    = (const float*)d_in[8];
  const float* w_ih0  = (const float*)d_in[9];
  const float* w_hh0  = (const float*)d_in[10];
  const float* b_ih0  = (const float*)d_in[11];
  const float* b_hh0  = (const float*)d_in[12];
  const float* w_ih1  = (const float*)d_in[13];
  const float* w_hh1  = (const float*)d_in[14];
  const float* b_ih1  = (const float*)d_in[15];
  const float* b_hh1  = (const float*)d_in[16];
  const float* fc_w   = (const float*)d_in[17];
  const float* fc_b   = (const float*)d_in[18];

  float* out  = (float*)d_out;
  float* pred = out;                 // [64,32000]
  float* nh   = out + 2048000;       // [2,64,1024]
  float* nc   = out + 2179072;       // [2,64,1024]
  float* aw   = out + 2310144;       // [64,128]

  char*  wsb   = (char*)d_ws;
  short* encbf = (short*)(wsb + 0);          // 16,777,216 B
  short* Wbf   = (short*)(wsb + 16777216);   //  1,048,576 B
  short* A0    = (short*)(wsb + 17825792);   //    327,680 B
  short* A1    = (short*)(wsb + 18153472);   //    262,144 B
  short* Zb    = (short*)(wsb + 18415616);   //    327,680 B
  float* sco   = (float*)(wsb + 18743296);   //     32,768 B
  float* Pb    = (float*)(wsb + 18776064);   // split-K partials

  size_t avail = ws_size > 18776064 ? ws_size - 18776064 : 0;
  // fc needs KSf*8.192MB; gates need KSg*1.049MB (max 20.97MB)
  int KSf  = avail >= 33554432ul ? 4 : avail >= 16777216ul ? 2 : 1;
  int KSg0 = avail >= 20971520ul ? 20 : 4;   // 2560/KSg0 must be mult of 32
  int KSg1 = avail >= 16777216ul ? 16 : 4;

  prep_all<<<4404, 256, 0, stream>>>(tok, emb, hidden, enc, attn_w,
                                     encbf, Wbf, A0, A1, Zb, sco);

  energy_k<<<1024, 256, 0, stream>>>(encbf, Wbf, hidden + 65536,
                                     attn_w, attn_b, v_w, sco);

  ctxsm_k<<<dim3(64, 4), 256, 0, stream>>>(sco, mask, encbf, aw, A0, Zb);

  // layer 0: A0 = [emb | ctx | h0_prev], W = [w_ih0 | w_hh0], K=2560
  gemm2<1><<<dim3(64, KSg0), 256, 0, stream>>>(A0, 2560,
                                               w_ih0, 1536, 1536, w_hh0, 1024,
                                               2560 / KSg0, Pb, 4096);
  lstm_k<<<256, 256, 0, stream>>>(Pb, KSg0, b_ih0, b_hh0, cell,
                                  nh, nc, A1, 2048);

  // layer 1: A1 = [h0' | h1_prev], W = [w_ih1 | w_hh1], K=2048
  gemm2<1><<<dim3(64, KSg1), 256, 0, stream>>>(A1, 2048,
                                               w_ih1, 1024, 1024, w_hh1, 1024,
                                               2048 / KSg1, Pb, 4096);
  lstm_k<<<256, 256, 0, stream>>>(Pb, KSg1, b_ih1, b_hh1, cell + 65536,
                                  nh + 65536, nc + 65536, Zb, 2560);

  // prediction = Zb @ fc_w^T + fc_b, NT=2 -> 128 cols/block
  gemm2<2><<<dim3(250, KSf), 256, 0, stream>>>(Zb, 2560,
                                               fc_w, 2560, 2560, nullptr, 0,
                                               2560 / KSf, Pb, 32000);
  reduce_k<<<dim3(32, 64), 256, 0, stream>>>(Pb, KSf, fc_b, pred, 32000);
}

// Round 5
// 290.943 us; speedup vs baseline: 2.5383x; 1.1478x over previous
//
#include <hip/hip_runtime.h>

// Decoder step: embed -> additive attention -> 2-layer LSTM -> fc
// B=64, S=128, E=512, H=512, H2=1024, V=32000
// Streaming GEMMs: bf16 MFMA 16x16x32. W streamed f32 via async
// global_load_lds (width 16) into a 3-buffer LDS rotation, barrier-free
// (each wave stages exactly the 16 W-rows it consumes; per-wave vmcnt sync).
// LDS layout XOR-swizzled via pre-swizzled global source (bank-conflict-free).

typedef __attribute__((ext_vector_type(8))) short bf16x8;
typedef __attribute__((ext_vector_type(4))) float f32x4;

__device__ __forceinline__ short f2bf(float f){
  __bf16 h = (__bf16)f;
  return __builtin_bit_cast(short, h);
}

__device__ __forceinline__ bf16x8 cvt8(float4 a, float4 b){
  bf16x8 r;
  r[0]=f2bf(a.x); r[1]=f2bf(a.y); r[2]=f2bf(a.z); r[3]=f2bf(a.w);
  r[4]=f2bf(b.x); r[5]=f2bf(b.y); r[6]=f2bf(b.z); r[7]=f2bf(b.w);
  return r;
}

__device__ __forceinline__ bf16x8 ld8_bf(const float* __restrict__ p){
  return cvt8(*(const float4*)p, *(const float4*)(p + 4));
}

__device__ __forceinline__ float fast_tanh(float x){
  x = fminf(fmaxf(x, -15.f), 15.f);
  float t = __expf(2.f * x);
  return (t - 1.f) / (t + 1.f);
}
__device__ __forceinline__ float fast_sig(float x){
  return 1.f / (1.f + __expf(-x));
}

__device__ __forceinline__ void stage16(const float* src, float* dst_lds){
  __builtin_amdgcn_global_load_lds(
      (const __attribute__((address_space(1))) void*)src,
      (__attribute__((address_space(3))) void*)dst_lds, 16, 0, 0);
}

// ---------------------------------------------------------------------------
// Fused prep: enc->bf16, attn_w[:,1024:2048]->bf16, emb gather, hidden cvt,
// scores zero.
// ---------------------------------------------------------------------------
__global__ __launch_bounds__(256) void prep_all(
    const int* __restrict__ tok, const float* __restrict__ emb,
    const float* __restrict__ hidden, const float* __restrict__ enc,
    const float* __restrict__ attn_w,
    short* __restrict__ encbf, short* __restrict__ Wbf,
    short* __restrict__ A0, short* __restrict__ A1, short* __restrict__ Zb,
    float* __restrict__ sco)
{
  const int bid = blockIdx.x, t = threadIdx.x;
  if (bid < 4096){
    long i = ((long)bid*256 + t)*8;
    *(bf16x8*)(encbf + i) = ld8_bf(enc + i);
  } else if (bid < 4352){
    int j = (bid-4096)*256 + t;
    int r = j >> 7, c = (j & 127)*8;
    *(bf16x8*)(Wbf + r*1024 + c) = ld8_bf(attn_w + (long)r*2048 + 1024 + c);
  } else if (bid < 4368){
    int j = (bid-4352)*256 + t;
    int b = j >> 6, e8 = (j & 63)*8;
    bf16x8 v = ld8_bf(emb + (long)tok[b]*512 + e8);
    *(bf16x8*)(A0 + b*2560 + e8) = v;
    *(bf16x8*)(Zb + b*2560 + 2048 + e8) = v;
  } else if (bid < 4400){
    int j = (bid-4368)*256 + t;
    int b = j >> 7, n8 = (j & 127)*8;
    *(bf16x8*)(A0 + b*2560 + 1536 + n8) = ld8_bf(hidden + (long)b*1024 + n8);
    *(bf16x8*)(A1 + b*2048 + 1024 + n8) = ld8_bf(hidden + 65536 + (long)b*1024 + n8);
  } else {
    int j = (bid-4400)*256 + t;
    float4 z = {0.f, 0.f, 0.f, 0.f};
    *(float4*)(sco + j*8) = z;
    *(float4*)(sco + j*8 + 4) = z;
  }
}

// ---------------------------------------------------------------------------
// P[by][64][N] = A_bf16[64,K] @ [W1|W2][N,:]^T on k-slice by.
// Block: 4 waves x 16 n-cols = 64 cols. W rows streamed f32 -> LDS via
// global_load_lds (each wave stages rows [16w,16w+16) of each 64-k buffer;
// 3-buffer rotation; no barriers). K1/W2 boundary must be 64-aligned.
// ---------------------------------------------------------------------------
__global__ __launch_bounds__(256) void gemm_lds(
    const short* __restrict__ A, int lda,
    const float* __restrict__ W1, int sW1, int K1,
    const float* __restrict__ W2, int sW2,
    int Kslice, float* __restrict__ P, int N)
{
  __shared__ float lds[3][64*64];
  const int wv   = threadIdx.x >> 6;
  const int lane = threadIdx.x & 63;
  const int l15  = lane & 15;
  const int lg   = lane >> 4;
  const int nb   = blockIdx.x * 64;
  const int k0   = blockIdx.y * Kslice;
  const int NT   = Kslice >> 6;

  auto STAGE = [&](int bi, int kbase){
    const int kg = k0 + kbase;
    const float* W; long sW; int kw;
    if (kg < K1){ W = W1; sW = sW1; kw = kg; }
    else        { W = W2; sW = sW2; kw = kg - K1; }
    #pragma unroll
    for (int i = 0; i < 4; ++i){
      int row = wv*16 + i*4 + lg;                    // lg = lane>>4 here: 4 rows/inst
      int swz = ((lane & 15)*16) ^ ((row & 7) << 4); // pre-swizzled source bytes
      const float* src = W + (long)(nb + row)*sW + kw + (swz >> 2);
      stage16(src, &lds[bi][(wv*16 + i*4)*64]);
    }
  };

  const int rl = wv*16 + l15;            // LDS row this lane consumes
  const int sw = (rl & 7) << 4;

  f32x4 acc[4];
  #pragma unroll
  for (int m = 0; m < 4; ++m) acc[m] = (f32x4){0.f,0.f,0.f,0.f};

  auto COMPUTE = [&](int bi, int kbase){
    const short* apk = A + (long)l15*lda + k0 + kbase + lg*8;
    bf16x8 a0[4], a1[4];
    #pragma unroll
    for (int m = 0; m < 4; ++m){
      a0[m] = *(const bf16x8*)(apk + m*16*lda);
      a1[m] = *(const bf16x8*)(apk + 32 + m*16*lda);
    }
    const char* rb = (const char*)&lds[bi][0] + rl*256;
    float4 w00 = *(const float4*)(rb + ((lg*32      ) ^ sw));
    float4 w01 = *(const float4*)(rb + ((lg*32 + 16 ) ^ sw));
    float4 w10 = *(const float4*)(rb + ((lg*32 + 128) ^ sw));
    float4 w11 = *(const float4*)(rb + ((lg*32 + 144) ^ sw));
    bf16x8 wf0 = cvt8(w00, w01);
    bf16x8 wf1 = cvt8(w10, w11);
    #pragma unroll
    for (int m = 0; m < 4; ++m)
      acc[m] = __builtin_amdgcn_mfma_f32_16x16x32_bf16(a0[m], wf0, acc[m], 0,0,0);
    #pragma unroll
    for (int m = 0; m < 4; ++m)
      acc[m] = __builtin_amdgcn_mfma_f32_16x16x32_bf16(a1[m], wf1, acc[m], 0,0,0);
  };

  STAGE(0, 0);
  if (NT > 1) STAGE(1, 64);
  int t = 0;
  for (; t < NT-1; ++t){
    asm volatile("s_waitcnt vmcnt(4)" ::: "memory");   // buffer t staged
    COMPUTE(t % 3, t*64);
    if (t+2 < NT) STAGE((t+2) % 3, (t+2)*64);
  }
  asm volatile("s_waitcnt vmcnt(0)" ::: "memory");
  COMPUTE(t % 3, t*64);

  float* p = P + (long)blockIdx.y * 64 * N;
  #pragma unroll
  for (int mt = 0; mt < 4; ++mt)
    #pragma unroll
    for (int r = 0; r < 4; ++r){
      int m = mt*16 + lg*4 + r;
      p[(long)m * N + nb + wv*16 + l15] = acc[mt][r];
    }
}

// C[m][n] = sum_s P[s][m][n] + bias[n]   (float4)
__global__ __launch_bounds__(256) void reduce_k(
    const float* __restrict__ P, int KS, const float* __restrict__ bias,
    float* __restrict__ C, int N)
{
  const int n4 = (blockIdx.x * 256 + threadIdx.x) * 4;
  if (n4 >= N) return;
  const int m = blockIdx.y;
  const long sl = (long)64 * N;
  float4 s = *(const float4*)(bias + n4);
  const float* p = P + (long)m * N + n4;
  for (int k = 0; k < KS; ++k){
    float4 v = *(const float4*)(p + k * sl);
    s.x += v.x; s.y += v.y; s.z += v.z; s.w += v.w;
  }
  *(float4*)(C + (long)m * N + n4) = s;
}

// ---------------------------------------------------------------------------
// energy: T = encbf @ Wbf^T, scores[m] += v . tanh(T + hraw + attn_b)
// grid 1024: m3 = bx&127 (fast -> XCD id) for enc L2 reuse.
// ---------------------------------------------------------------------------
__global__ __launch_bounds__(256) void energy_k(
    const short* __restrict__ encbf, const short* __restrict__ Wbf,
    const float* __restrict__ hraw, const float* __restrict__ attn_b,
    const float* __restrict__ v_w, float* __restrict__ scores)
{
  const int bx = blockIdx.x;
  const int m3 = bx & 127, n3 = bx >> 7;
  const int wave = threadIdx.x >> 6;
  const int lane = threadIdx.x & 63;
  const int l15  = lane & 15;
  const int lg   = lane >> 4;
  const int mb   = m3 * 64;
  const int nb   = n3 * 64 + wave * 16;
  const int b    = mb >> 7;

  const float hp = hraw[(long)b*512 + nb + l15] + attn_b[nb + l15];

  f32x4 acc[4] = {};
  const short* ap  = encbf + (long)(mb + l15) * 1024 + lg * 8;
  const short* wpb = Wbf   + (long)(nb + l15) * 1024 + lg * 8;

  bf16x8 wn  = *(const bf16x8*)(wpb);
  bf16x8 an0 = *(const bf16x8*)(ap);
  bf16x8 an1 = *(const bf16x8*)(ap + 16*1024);
  bf16x8 an2 = *(const bf16x8*)(ap + 32*1024);
  bf16x8 an3 = *(const bf16x8*)(ap + 48*1024);
  for (int kb = 32; kb < 1024; kb += 32){
    bf16x8 wc = wn, c0 = an0, c1 = an1, c2 = an2, c3 = an3;
    wn  = *(const bf16x8*)(wpb + kb);
    an0 = *(const bf16x8*)(ap + kb);
    an1 = *(const bf16x8*)(ap + kb + 16*1024);
    an2 = *(const bf16x8*)(ap + kb + 32*1024);
    an3 = *(const bf16x8*)(ap + kb + 48*1024);
    acc[0] = __builtin_amdgcn_mfma_f32_16x16x32_bf16(c0, wc, acc[0], 0,0,0);
    acc[1] = __builtin_amdgcn_mfma_f32_16x16x32_bf16(c1, wc, acc[1], 0,0,0);
    acc[2] = __builtin_amdgcn_mfma_f32_16x16x32_bf16(c2, wc, acc[2], 0,0,0);
    acc[3] = __builtin_amdgcn_mfma_f32_16x16x32_bf16(c3, wc, acc[3], 0,0,0);
  }
  acc[0] = __builtin_amdgcn_mfma_f32_16x16x32_bf16(an0, wn, acc[0], 0,0,0);
  acc[1] = __builtin_amdgcn_mfma_f32_16x16x32_bf16(an1, wn, acc[1], 0,0,0);
  acc[2] = __builtin_amdgcn_mfma_f32_16x16x32_bf16(an2, wn, acc[2], 0,0,0);
  acc[3] = __builtin_amdgcn_mfma_f32_16x16x32_bf16(an3, wn, acc[3], 0,0,0);

  const float vn = v_w[nb + l15];
  #pragma unroll
  for (int mt = 0; mt < 4; ++mt){
    #pragma unroll
    for (int r = 0; r < 4; ++r){
      int m = mb + mt*16 + lg*4 + r;
      float e = fast_tanh(acc[mt][r] + hp) * vn;
      e += __shfl_xor(e, 1, 16);
      e += __shfl_xor(e, 2, 16);
      e += __shfl_xor(e, 4, 16);
      e += __shfl_xor(e, 8, 16);
      if (l15 == 0) atomicAdd(&scores[m], e);
    }
  }
}

// Fused masked softmax + context
__global__ __launch_bounds__(256) void ctxsm_k(
    const float* __restrict__ sco, const int* __restrict__ mask,
    const short* __restrict__ encbf, float* __restrict__ aw,
    short* __restrict__ A0, short* __restrict__ Zb)
{
  const int bb = blockIdx.x;
  const int t  = threadIdx.x;
  __shared__ float red[128];
  __shared__ float w[128];
  float v = 0.f;
  if (t < 128){
    v = sco[bb*128 + t];
    if (mask[bb*128 + t] == 0) v = -1e10f;
    red[t] = v;
  }
  __syncthreads();
  for (int d = 64; d > 0; d >>= 1){
    if (t < d) red[t] = fmaxf(red[t], red[t + d]);
    __syncthreads();
  }
  const float mx = red[0];
  __syncthreads();
  if (t < 128){
    float e = __expf(v - mx);
    w[t] = e; red[t] = e;
  }
  __syncthreads();
  for (int d = 64; d > 0; d >>= 1){
    if (t < d) red[t] += red[t + d];
    __syncthreads();
  }
  const float inv = 1.f / red[0];
  if (blockIdx.y == 0 && t < 128) aw[bb*128 + t] = w[t] * inv;

  const int dd = blockIdx.y * 256 + t;
  const unsigned short* e = (const unsigned short*)encbf + (long)bb*131072 + dd;
  float s = 0.f;
  #pragma unroll 4
  for (int si = 0; si < 128; ++si){
    float ev = __builtin_bit_cast(float, (unsigned)e[si*1024] << 16);
    s += w[si] * ev;
  }
  s *= inv;
  short vbf = f2bf(s);
  A0[bb*2560 + 512  + dd] = vbf;
  Zb[bb*2560 + 1024 + dd] = vbf;
}

// LSTM epilogue with fused split-K reduce
__global__ __launch_bounds__(256) void lstm_k(
    const float* __restrict__ P, int KS,
    const float* __restrict__ bi, const float* __restrict__ bh,
    const float* __restrict__ c_prev,
    float* __restrict__ h_out, float* __restrict__ c_out,
    short* __restrict__ h_bf, int bf_stride)
{
  const int i = blockIdx.x * 256 + threadIdx.x;
  const int b = i >> 10, n = i & 1023;
  float g4[4];
  #pragma unroll
  for (int gi = 0; gi < 4; ++gi){
    int col = gi*1024 + n;
    float s = bi[col] + bh[col];
    const float* p = P + (long)b*4096 + col;
    for (int sl = 0; sl < KS; ++sl) s += p[(long)sl * 262144];
    g4[gi] = s;
  }
  float iv = fast_sig (g4[0]);
  float fv = fast_sig (g4[1]);
  float gv = fast_tanh(g4[2]);
  float ov = fast_sig (g4[3]);
  float c = fv * c_prev[i] + iv * gv;
  float h = ov * fast_tanh(c);
  c_out[i] = c;
  h_out[i] = h;
  h_bf[(long)b * bf_stride + n] = f2bf(h);
}

extern "C" void kernel_launch(void* const* d_in, const int* in_sizes, int n_in,
                              void* d_out, int out_size, void* d_ws, size_t ws_size,
                              hipStream_t stream)
{
  const int*   tok    = (const int*)  d_in[0];
  const float* hidden = (const float*)d_in[1];
  const float* cell   = (const float*)d_in[2];
  const float* enc    = (const float*)d_in[3];
  const int*   mask   = (const int*)  d_in[4];
  const float* emb    = (const float*)d_in[5];
  const float* attn_w = (const float*)d_in[6];
  const float* attn_b = (const float*)d_in[7];
  const float* v_w    = (const float*)d_in[8];
  const float* w_ih0  = (const float*)d_in[9];
  const float* w_hh0  = (const float*)d_in[10];
  const float* b_ih0  = (const float*)d_in[11];
  const float* b_hh0  = (const float*)d_in[12];
  const float* w_ih1  = (const float*)d_in[13];
  const float* w_hh1  = (const float*)d_in[14];
  const float* b_ih1  = (const float*)d_in[15];
  const float* b_hh1  = (const float*)d_in[16];
  const float* fc_w   = (const float*)d_in[17];
  const float* fc_b   = (const float*)d_in[18];

  float* out  = (float*)d_out;
  float* pred = out;                 // [64,32000]
  float* nh   = out + 2048000;       // [2,64,1024]
  float* nc   = out + 2179072;       // [2,64,1024]
  float* aw   = out + 2310144;       // [64,128]

  char*  wsb   = (char*)d_ws;
  short* encbf = (short*)(wsb + 0);          // 16,777,216 B
  short* Wbf   = (short*)(wsb + 16777216);   //  1,048,576 B
  short* A0    = (short*)(wsb + 17825792);   //    327,680 B
  short* A1    = (short*)(wsb + 18153472);   //    262,144 B
  short* Zb    = (short*)(wsb + 18415616);   //    327,680 B
  float* sco   = (float*)(wsb + 18743296);   //     32,768 B
  float* Ph    = (float*)(wsb + 18776064);   //    131,072 B  hproj raw
  float* Pb    = (float*)(wsb + 18907136);   // split-K partials

  size_t avail = ws_size > 18907136 ? ws_size - 18907136 : 0;
  // Kslice must be a multiple of 64 and align with the K1 boundary (64-mult).
  int KSf = avail >= 16500000ul ? 2 : 1;     // fc: KSf*8.192 MB
  int KSg = avail >=  8400000ul ? 8 : 4;     // gates: KSg*1.049 MB

  prep_all<<<4404, 256, 0, stream>>>(tok, emb, hidden, enc, attn_w,
                                     encbf, Wbf, A0, A1, Zb, sco);

  // hproj_raw = h_top @ attn_w[:,0:1024]^T  (bias folded into energy)
  gemm_lds<<<dim3(8, 1), 256, 0, stream>>>(A1 + 1024, 2048,
                                           attn_w, 2048, 1<<30, nullptr, 0,
                                           1024, Ph, 512);

  energy_k<<<1024, 256, 0, stream>>>(encbf, Wbf, Ph, attn_b, v_w, sco);

  ctxsm_k<<<dim3(64, 4), 256, 0, stream>>>(sco, mask, encbf, aw, A0, Zb);

  // layer 0: A0 = [emb | ctx | h0_prev], W = [w_ih0 | w_hh0], K=2560, K1=1536
  gemm_lds<<<dim3(64, KSg), 256, 0, stream>>>(A0, 2560,
                                              w_ih0, 1536, 1536, w_hh0, 1024,
                                              2560 / KSg, Pb, 4096);
  lstm_k<<<256, 256, 0, stream>>>(Pb, KSg, b_ih0, b_hh0, cell,
                                  nh, nc, A1, 2048);

  // layer 1: A1 = [h0' | h1_prev], W = [w_ih1 | w_hh1], K=2048, K1=1024
  gemm_lds<<<dim3(64, KSg), 256, 0, stream>>>(A1, 2048,
                                              w_ih1, 1024, 1024, w_hh1, 1024,
                                              2048 / KSg, Pb, 4096);
  lstm_k<<<256, 256, 0, stream>>>(Pb, KSg, b_ih1, b_hh1, cell + 65536,
                                  nh + 65536, nc + 65536, Zb, 2560);

  // prediction = Zb @ fc_w^T + fc_b
  gemm_lds<<<dim3(500, KSf), 256, 0, stream>>>(Zb, 2560,
                                               fc_w, 2560, 1<<30, nullptr, 0,
                                               2560 / KSf, Pb, 32000);
  reduce_k<<<dim3(32, 64), 256, 0, stream>>>(Pb, KSf, fc_b, pred, 32000);
}

// Round 6
// 249.169 us; speedup vs baseline: 2.9638x; 1.1677x over previous
//
#include <hip/hip_runtime.h>

// Decoder step: embed -> additive attention -> 2-layer LSTM -> fc
// B=64, S=128, E=512, H=512, H2=1024, V=32000
// GEMMs: bf16 MFMA 16x16x32. A-slice staged once into LDS (XOR-swizzled via
// pre-swizzled global source), read via ds_read_b128 (lgkmcnt domain).
// W streamed f32 via global_load_lds into 3-buffer LDS rotation with counted
// vmcnt(4) waits only (vmcnt-pure staging pipeline, never drained mid-loop).

typedef __attribute__((ext_vector_type(8))) short bf16x8;
typedef __attribute__((ext_vector_type(4))) float f32x4;

__device__ __forceinline__ short f2bf(float f){
  __bf16 h = (__bf16)f;
  return __builtin_bit_cast(short, h);
}

__device__ __forceinline__ bf16x8 cvt8(float4 a, float4 b){
  bf16x8 r;
  r[0]=f2bf(a.x); r[1]=f2bf(a.y); r[2]=f2bf(a.z); r[3]=f2bf(a.w);
  r[4]=f2bf(b.x); r[5]=f2bf(b.y); r[6]=f2bf(b.z); r[7]=f2bf(b.w);
  return r;
}

__device__ __forceinline__ bf16x8 ld8_bf(const float* __restrict__ p){
  return cvt8(*(const float4*)p, *(const float4*)(p + 4));
}

__device__ __forceinline__ float fast_tanh(float x){
  x = fminf(fmaxf(x, -15.f), 15.f);
  float t = __expf(2.f * x);
  return (t - 1.f) / (t + 1.f);
}
__device__ __forceinline__ float fast_sig(float x){
  return 1.f / (1.f + __expf(-x));
}

__device__ __forceinline__ void stage16(const void* src, void* dst_lds){
  __builtin_amdgcn_global_load_lds(
      (const __attribute__((address_space(1))) void*)src,
      (__attribute__((address_space(3))) void*)dst_lds, 16, 0, 0);
}

// ---------------------------------------------------------------------------
// Fused prep: enc->bf16, attn_w[:,1024:2048]->bf16, emb gather, hidden cvt,
// scores zero.
// ---------------------------------------------------------------------------
__global__ __launch_bounds__(256) void prep_all(
    const int* __restrict__ tok, const float* __restrict__ emb,
    const float* __restrict__ hidden, const float* __restrict__ enc,
    const float* __restrict__ attn_w,
    short* __restrict__ encbf, short* __restrict__ Wbf,
    short* __restrict__ A0, short* __restrict__ A1, short* __restrict__ Zb,
    float* __restrict__ sco)
{
  const int bid = blockIdx.x, t = threadIdx.x;
  if (bid < 4096){
    long i = ((long)bid*256 + t)*8;
    *(bf16x8*)(encbf + i) = ld8_bf(enc + i);
  } else if (bid < 4352){
    int j = (bid-4096)*256 + t;
    int r = j >> 7, c = (j & 127)*8;
    *(bf16x8*)(Wbf + r*1024 + c) = ld8_bf(attn_w + (long)r*2048 + 1024 + c);
  } else if (bid < 4368){
    int j = (bid-4352)*256 + t;
    int b = j >> 6, e8 = (j & 63)*8;
    bf16x8 v = ld8_bf(emb + (long)tok[b]*512 + e8);
    *(bf16x8*)(A0 + b*2560 + e8) = v;
    *(bf16x8*)(Zb + b*2560 + 2048 + e8) = v;
  } else if (bid < 4400){
    int j = (bid-4368)*256 + t;
    int b = j >> 7, n8 = (j & 127)*8;
    *(bf16x8*)(A0 + b*2560 + 1536 + n8) = ld8_bf(hidden + (long)b*1024 + n8);
    *(bf16x8*)(A1 + b*2048 + 1024 + n8) = ld8_bf(hidden + 65536 + (long)b*1024 + n8);
  } else {
    int j = (bid-4400)*256 + t;
    float4 z = {0.f, 0.f, 0.f, 0.f};
    *(float4*)(sco + j*8) = z;
    *(float4*)(sco + j*8 + 4) = z;
  }
}

// ---------------------------------------------------------------------------
// P[by][64][N] = A_bf16[64,K] @ [W1|W2][N,:]^T on a 256-wide k-slice.
// A-slice in LDS (swizzled), W via 3-buffer global_load_lds rotation.
// K1 (W1/W2 boundary) must be a multiple of 256.
// ---------------------------------------------------------------------------
#define KSL 256
__global__ __launch_bounds__(256) void gemm_lds(
    const short* __restrict__ A, int lda,
    const float* __restrict__ W1, int sW1, int K1,
    const float* __restrict__ W2, int sW2,
    float* __restrict__ P, int N)
{
  __shared__ short Al[64*256];     // 32 KB  (A slice, XOR-swizzled rows)
  __shared__ float Wl[3][64*64];   // 48 KB  (W f32 staging buffers)
  const int wv   = threadIdx.x >> 6;
  const int lane = threadIdx.x & 63;
  const int l15  = lane & 15;
  const int lg   = lane >> 4;
  const int nb   = blockIdx.x * 64;
  const int k0   = blockIdx.y * KSL;

  const float* W; int sW, koff;
  if (k0 < K1){ W = W1; sW = sW1; koff = k0; }
  else        { W = W2; sW = sW2; koff = k0 - K1; }

  // ---- stage A slice: rows [wv*16, wv*16+16), 2 rows per inst ----
  {
    const int r2  = lane >> 5;
    const int c16 = (lane & 31) * 16;
    #pragma unroll
    for (int i = 0; i < 8; ++i){
      int rbase = wv*16 + i*2;
      int row   = rbase + r2;
      const char* src = (const char*)A + (long)row*lda*2 + (long)k0*2
                        + (c16 ^ ((row & 7) << 4));
      stage16(src, (void*)(Al + rbase*256));
    }
  }

  auto STAGEW = [&](int bi, int kbase){
    #pragma unroll
    for (int i = 0; i < 4; ++i){
      int row = wv*16 + i*4 + lg;
      const char* src = (const char*)(W + (long)(nb + row)*sW + koff + kbase)
                        + ((l15*16) ^ ((row & 7) << 4));
      stage16(src, (void*)&Wl[bi][(wv*16 + i*4)*64]);
    }
  };

  STAGEW(0, 0);
  STAGEW(1, 64);
  asm volatile("s_waitcnt vmcnt(8)" ::: "memory");   // A staged (W0,W1 in flight)
  asm volatile("s_barrier" ::: "memory");

  f32x4 acc[4];
  #pragma unroll
  for (int m = 0; m < 4; ++m) acc[m] = (f32x4){0.f,0.f,0.f,0.f};

  const int  rl = wv*16 + l15;          // W LDS row this lane consumes
  const int  sw = (l15 & 7) << 4;       // shared XOR swizzle (row&7 == l15&7)
  const char* wbase = (const char*)&Wl[0][0];
  const char* abase = (const char*)Al;

  auto COMPUTE = [&](int bi, int t){
    bf16x8 a[4][2];
    #pragma unroll
    for (int m = 0; m < 4; ++m)
      #pragma unroll
      for (int h = 0; h < 2; ++h){
        int cb = t*128 + h*64 + lg*16;
        a[m][h] = *(const bf16x8*)(abase + (m*16 + l15)*512 + (cb ^ sw));
      }
    const char* rb = wbase + bi*16384 + rl*256;
    float4 w00 = *(const float4*)(rb + ((lg*32      ) ^ sw));
    float4 w01 = *(const float4*)(rb + ((lg*32 + 16 ) ^ sw));
    float4 w10 = *(const float4*)(rb + ((lg*32 + 128) ^ sw));
    float4 w11 = *(const float4*)(rb + ((lg*32 + 144) ^ sw));
    bf16x8 wf0 = cvt8(w00, w01);
    bf16x8 wf1 = cvt8(w10, w11);
    #pragma unroll
    for (int m = 0; m < 4; ++m)
      acc[m] = __builtin_amdgcn_mfma_f32_16x16x32_bf16(a[m][0], wf0, acc[m], 0,0,0);
    #pragma unroll
    for (int m = 0; m < 4; ++m)
      acc[m] = __builtin_amdgcn_mfma_f32_16x16x32_bf16(a[m][1], wf1, acc[m], 0,0,0);
  };

  asm volatile("s_waitcnt vmcnt(4)" ::: "memory");   // W0 ready
  COMPUTE(0, 0);
  STAGEW(2, 128);
  asm volatile("s_waitcnt vmcnt(4)" ::: "memory");   // W1 ready
  COMPUTE(1, 1);
  STAGEW(0, 192);
  asm volatile("s_waitcnt vmcnt(4)" ::: "memory");   // W2 ready
  COMPUTE(2, 2);
  asm volatile("s_waitcnt vmcnt(0)" ::: "memory");   // W0' ready
  COMPUTE(0, 3);

  float* p = P + (long)blockIdx.y * 64 * N;
  #pragma unroll
  for (int mt = 0; mt < 4; ++mt)
    #pragma unroll
    for (int r = 0; r < 4; ++r){
      int m = mt*16 + lg*4 + r;
      p[(long)m * N + nb + wv*16 + l15] = acc[mt][r];
    }
}

// C[m][n] = sum_s P[s][m][n] + bias[n]   (float4)
__global__ __launch_bounds__(256) void reduce_k(
    const float* __restrict__ P, int KS, const float* __restrict__ bias,
    float* __restrict__ C, int N)
{
  const int n4 = (blockIdx.x * 256 + threadIdx.x) * 4;
  if (n4 >= N) return;
  const int m = blockIdx.y;
  const long sl = (long)64 * N;
  float4 s = *(const float4*)(bias + n4);
  const float* p = P + (long)m * N + n4;
  for (int k = 0; k < KS; ++k){
    float4 v = *(const float4*)(p + k * sl);
    s.x += v.x; s.y += v.y; s.z += v.z; s.w += v.w;
  }
  *(float4*)(C + (long)m * N + n4) = s;
}

// ---------------------------------------------------------------------------
// energy: T = encbf @ Wbf^T, scores[m] += v . tanh(T + hproj[b,n])
// hproj (bias already folded) from LDS-GEMM. grid 1024: m3 = bx&127 -> XCD id.
// ---------------------------------------------------------------------------
__global__ __launch_bounds__(256) void energy_k(
    const short* __restrict__ encbf, const short* __restrict__ Wbf,
    const float* __restrict__ hproj, const float* __restrict__ v_w,
    float* __restrict__ scores)
{
  const int bx = blockIdx.x;
  const int m3 = bx & 127, n3 = bx >> 7;
  const int wave = threadIdx.x >> 6;
  const int lane = threadIdx.x & 63;
  const int l15  = lane & 15;
  const int lg   = lane >> 4;
  const int mb   = m3 * 64;
  const int nb   = n3 * 64 + wave * 16;
  const int b    = mb >> 7;

  const float hp = hproj[(long)b*512 + nb + l15];

  f32x4 acc[4] = {};
  const short* ap  = encbf + (long)(mb + l15) * 1024 + lg * 8;
  const short* wpb = Wbf   + (long)(nb + l15) * 1024 + lg * 8;

  bf16x8 wn  = *(const bf16x8*)(wpb);
  bf16x8 an0 = *(const bf16x8*)(ap);
  bf16x8 an1 = *(const bf16x8*)(ap + 16*1024);
  bf16x8 an2 = *(const bf16x8*)(ap + 32*1024);
  bf16x8 an3 = *(const bf16x8*)(ap + 48*1024);
  for (int kb = 32; kb < 1024; kb += 32){
    bf16x8 wc = wn, c0 = an0, c1 = an1, c2 = an2, c3 = an3;
    wn  = *(const bf16x8*)(wpb + kb);
    an0 = *(const bf16x8*)(ap + kb);
    an1 = *(const bf16x8*)(ap + kb + 16*1024);
    an2 = *(const bf16x8*)(ap + kb + 32*1024);
    an3 = *(const bf16x8*)(ap + kb + 48*1024);
    acc[0] = __builtin_amdgcn_mfma_f32_16x16x32_bf16(c0, wc, acc[0], 0,0,0);
    acc[1] = __builtin_amdgcn_mfma_f32_16x16x32_bf16(c1, wc, acc[1], 0,0,0);
    acc[2] = __builtin_amdgcn_mfma_f32_16x16x32_bf16(c2, wc, acc[2], 0,0,0);
    acc[3] = __builtin_amdgcn_mfma_f32_16x16x32_bf16(c3, wc, acc[3], 0,0,0);
  }
  acc[0] = __builtin_amdgcn_mfma_f32_16x16x32_bf16(an0, wn, acc[0], 0,0,0);
  acc[1] = __builtin_amdgcn_mfma_f32_16x16x32_bf16(an1, wn, acc[1], 0,0,0);
  acc[2] = __builtin_amdgcn_mfma_f32_16x16x32_bf16(an2, wn, acc[2], 0,0,0);
  acc[3] = __builtin_amdgcn_mfma_f32_16x16x32_bf16(an3, wn, acc[3], 0,0,0);

  const float vn = v_w[nb + l15];
  #pragma unroll
  for (int mt = 0; mt < 4; ++mt){
    #pragma unroll
    for (int r = 0; r < 4; ++r){
      int m = mb + mt*16 + lg*4 + r;
      float e = fast_tanh(acc[mt][r] + hp) * vn;
      e += __shfl_xor(e, 1, 16);
      e += __shfl_xor(e, 2, 16);
      e += __shfl_xor(e, 4, 16);
      e += __shfl_xor(e, 8, 16);
      if (l15 == 0) atomicAdd(&scores[m], e);
    }
  }
}

// Fused masked softmax + context
__global__ __launch_bounds__(256) void ctxsm_k(
    const float* __restrict__ sco, const int* __restrict__ mask,
    const short* __restrict__ encbf, float* __restrict__ aw,
    short* __restrict__ A0, short* __restrict__ Zb)
{
  const int bb = blockIdx.x;
  const int t  = threadIdx.x;
  __shared__ float red[128];
  __shared__ float w[128];
  float v = 0.f;
  if (t < 128){
    v = sco[bb*128 + t];
    if (mask[bb*128 + t] == 0) v = -1e10f;
    red[t] = v;
  }
  __syncthreads();
  for (int d = 64; d > 0; d >>= 1){
    if (t < d) red[t] = fmaxf(red[t], red[t + d]);
    __syncthreads();
  }
  const float mx = red[0];
  __syncthreads();
  if (t < 128){
    float e = __expf(v - mx);
    w[t] = e; red[t] = e;
  }
  __syncthreads();
  for (int d = 64; d > 0; d >>= 1){
    if (t < d) red[t] += red[t + d];
    __syncthreads();
  }
  const float inv = 1.f / red[0];
  if (blockIdx.y == 0 && t < 128) aw[bb*128 + t] = w[t] * inv;

  const int dd = blockIdx.y * 256 + t;
  const unsigned short* e = (const unsigned short*)encbf + (long)bb*131072 + dd;
  float s = 0.f;
  #pragma unroll 4
  for (int si = 0; si < 128; ++si){
    float ev = __builtin_bit_cast(float, (unsigned)e[si*1024] << 16);
    s += w[si] * ev;
  }
  s *= inv;
  short vbf = f2bf(s);
  A0[bb*2560 + 512  + dd] = vbf;
  Zb[bb*2560 + 1024 + dd] = vbf;
}

// LSTM epilogue with fused split-K reduce
__global__ __launch_bounds__(256) void lstm_k(
    const float* __restrict__ P, int KS,
    const float* __restrict__ bi, const float* __restrict__ bh,
    const float* __restrict__ c_prev,
    float* __restrict__ h_out, float* __restrict__ c_out,
    short* __restrict__ h_bf, int bf_stride)
{
  const int i = blockIdx.x * 256 + threadIdx.x;
  const int b = i >> 10, n = i & 1023;
  float g4[4];
  #pragma unroll
  for (int gi = 0; gi < 4; ++gi){
    int col = gi*1024 + n;
    float s = bi[col] + bh[col];
    const float* p = P + (long)b*4096 + col;
    for (int sl = 0; sl < KS; ++sl) s += p[(long)sl * 262144];
    g4[gi] = s;
  }
  float iv = fast_sig (g4[0]);
  float fv = fast_sig (g4[1]);
  float gv = fast_tanh(g4[2]);
  float ov = fast_sig (g4[3]);
  float c = fv * c_prev[i] + iv * gv;
  float h = ov * fast_tanh(c);
  c_out[i] = c;
  h_out[i] = h;
  h_bf[(long)b * bf_stride + n] = f2bf(h);
}

extern "C" void kernel_launch(void* const* d_in, const int* in_sizes, int n_in,
                              void* d_out, int out_size, void* d_ws, size_t ws_size,
                              hipStream_t stream)
{
  const int*   tok    = (const int*)  d_in[0];
  const float* hidden = (const float*)d_in[1];
  const float* cell   = (const float*)d_in[2];
  const float* enc    = (const float*)d_in[3];
  const int*   mask   = (const int*)  d_in[4];
  const float* emb    = (const float*)d_in[5];
  const float* attn_w = (const float*)d_in[6];
  const float* attn_b = (const float*)d_in[7];
  const float* v_w    = (const float*)d_in[8];
  const float* w_ih0  = (const float*)d_in[9];
  const float* w_hh0  = (const float*)d_in[10];
  const float* b_ih0  = (const float*)d_in[11];
  const float* b_hh0  = (const float*)d_in[12];
  const float* w_ih1  = (const float*)d_in[13];
  const float* w_hh1  = (const float*)d_in[14];
  const float* b_ih1  = (const float*)d_in[15];
  const float* b_hh1  = (const float*)d_in[16];
  const float* fc_w   = (const float*)d_in[17];
  const float* fc_b   = (const float*)d_in[18];

  float* out  = (float*)d_out;
  float* pred = out;                 // [64,32000]
  float* nh   = out + 2048000;       // [2,64,1024]
  float* nc   = out + 2179072;       // [2,64,1024]
  float* aw   = out + 2310144;       // [64,128]

  char*  wsb   = (char*)d_ws;
  short* encbf = (short*)(wsb + 0);          // 16,777,216 B
  short* Wbf   = (short*)(wsb + 16777216);   //  1,048,576 B
  short* A0    = (short*)(wsb + 17825792);   //    327,680 B
  short* A1    = (short*)(wsb + 18153472);   //    262,144 B
  short* Zb    = (short*)(wsb + 18415616);   //    327,680 B
  float* sco   = (float*)(wsb + 18743296);   //     32,768 B
  float* Ph    = (float*)(wsb + 18776064);   //    131,072 B  hproj final
  float* Pb    = (float*)(wsb + 18907136);   // split-K partials (<= 82 MB)

  prep_all<<<4404, 256, 0, stream>>>(tok, emb, hidden, enc, attn_w,
                                     encbf, Wbf, A0, A1, Zb, sco);

  // hproj = h_top @ attn_w[:,0:1024]^T + attn_b  (K=1024 -> 4 slices)
  gemm_lds<<<dim3(8, 4), 256, 0, stream>>>(A1 + 1024, 2048,
                                           attn_w, 2048, 1<<30, nullptr, 0,
                                           Pb, 512);
  reduce_k<<<dim3(1, 64), 256, 0, stream>>>(Pb, 4, attn_b, Ph, 512);

  energy_k<<<1024, 256, 0, stream>>>(encbf, Wbf, Ph, v_w, sco);

  ctxsm_k<<<dim3(64, 4), 256, 0, stream>>>(sco, mask, encbf, aw, A0, Zb);

  // layer 0: A0 = [emb | ctx | h0_prev], W = [w_ih0 | w_hh0], K=2560
  gemm_lds<<<dim3(64, 10), 256, 0, stream>>>(A0, 2560,
                                             w_ih0, 1536, 1536, w_hh0, 1024,
                                             Pb, 4096);
  lstm_k<<<256, 256, 0, stream>>>(Pb, 10, b_ih0, b_hh0, cell,
                                  nh, nc, A1, 2048);

  // layer 1: A1 = [h0' | h1_prev], W = [w_ih1 | w_hh1], K=2048
  gemm_lds<<<dim3(64, 8), 256, 0, stream>>>(A1, 2048,
                                            w_ih1, 1024, 1024, w_hh1, 1024,
                                            Pb, 4096);
  lstm_k<<<256, 256, 0, stream>>>(Pb, 8, b_ih1, b_hh1, cell + 65536,
                                  nh + 65536, nc + 65536, Zb, 2560);

  // prediction = Zb @ fc_w^T + fc_b, K=2560 -> 10 slices
  gemm_lds<<<dim3(500, 10), 256, 0, stream>>>(Zb, 2560,
                                              fc_w, 2560, 1<<30, nullptr, 0,
                                              Pb, 32000);
  reduce_k<<<dim3(32, 64), 256, 0, stream>>>(Pb, 10, fc_b, pred, 32000);
}

// Round 7
// 217.666 us; speedup vs baseline: 3.3928x; 1.1447x over previous
//
#include <hip/hip_runtime.h>

// Decoder step: embed -> additive attention -> 2-layer LSTM -> fc
// B=64, S=128, E=512, H=512, H2=1024, V=32000
// GEMMs: bf16 MFMA 16x16x32. A staged to LDS (XOR-swizzled via pre-swizzled
// global source), W streamed f32 via global_load_lds with counted vmcnt waits
// (never drained mid-loop). fc: full-K 512-thread kernel, no split-K.

typedef __attribute__((ext_vector_type(8))) short bf16x8;
typedef __attribute__((ext_vector_type(4))) float f32x4;

__device__ __forceinline__ short f2bf(float f){
  __bf16 h = (__bf16)f;
  return __builtin_bit_cast(short, h);
}

__device__ __forceinline__ bf16x8 cvt8(float4 a, float4 b){
  bf16x8 r;
  r[0]=f2bf(a.x); r[1]=f2bf(a.y); r[2]=f2bf(a.z); r[3]=f2bf(a.w);
  r[4]=f2bf(b.x); r[5]=f2bf(b.y); r[6]=f2bf(b.z); r[7]=f2bf(b.w);
  return r;
}

__device__ __forceinline__ bf16x8 ld8_bf(const float* __restrict__ p){
  return cvt8(*(const float4*)p, *(const float4*)(p + 4));
}

__device__ __forceinline__ float fast_tanh(float x){
  x = fminf(fmaxf(x, -15.f), 15.f);
  float t = __expf(2.f * x);
  return (t - 1.f) / (t + 1.f);
}
__device__ __forceinline__ float fast_sig(float x){
  return 1.f / (1.f + __expf(-x));
}

__device__ __forceinline__ void stage16(const void* src, void* dst_lds){
  __builtin_amdgcn_global_load_lds(
      (const __attribute__((address_space(1))) void*)src,
      (__attribute__((address_space(3))) void*)dst_lds, 16, 0, 0);
}

// ---------------------------------------------------------------------------
// Fused prep: enc->bf16, attn_w[:,1024:2048]->bf16, emb gather, hidden cvt,
// scores zero.
// ---------------------------------------------------------------------------
__global__ __launch_bounds__(256) void prep_all(
    const int* __restrict__ tok, const float* __restrict__ emb,
    const float* __restrict__ hidden, const float* __restrict__ enc,
    const float* __restrict__ attn_w,
    short* __restrict__ encbf, short* __restrict__ Wbf,
    short* __restrict__ A0, short* __restrict__ A1, short* __restrict__ Zb,
    float* __restrict__ sco)
{
  const int bid = blockIdx.x, t = threadIdx.x;
  if (bid < 4096){
    long i = ((long)bid*256 + t)*8;
    *(bf16x8*)(encbf + i) = ld8_bf(enc + i);
  } else if (bid < 4352){
    int j = (bid-4096)*256 + t;
    int r = j >> 7, c = (j & 127)*8;
    *(bf16x8*)(Wbf + r*1024 + c) = ld8_bf(attn_w + (long)r*2048 + 1024 + c);
  } else if (bid < 4368){
    int j = (bid-4352)*256 + t;
    int b = j >> 6, e8 = (j & 63)*8;
    bf16x8 v = ld8_bf(emb + (long)tok[b]*512 + e8);
    *(bf16x8*)(A0 + b*2560 + e8) = v;
    *(bf16x8*)(Zb + b*2560 + 2048 + e8) = v;
  } else if (bid < 4400){
    int j = (bid-4368)*256 + t;
    int b = j >> 7, n8 = (j & 127)*8;
    *(bf16x8*)(A0 + b*2560 + 1536 + n8) = ld8_bf(hidden + (long)b*1024 + n8);
    *(bf16x8*)(A1 + b*2048 + 1024 + n8) = ld8_bf(hidden + 65536 + (long)b*1024 + n8);
  } else {
    int j = (bid-4400)*256 + t;
    float4 z = {0.f, 0.f, 0.f, 0.f};
    *(float4*)(sco + j*8) = z;
    *(float4*)(sco + j*8 + 4) = z;
  }
}

// ---------------------------------------------------------------------------
// P[by][64][N] = A_bf16[64,K] @ [W1|W2][N,:]^T on a 256-wide k-slice.
// (used for hproj + LSTM gates; split-K partials, consumer reduces)
// ---------------------------------------------------------------------------
#define KSL 256
__global__ __launch_bounds__(256) void gemm_lds(
    const short* __restrict__ A, int lda,
    const float* __restrict__ W1, int sW1, int K1,
    const float* __restrict__ W2, int sW2,
    float* __restrict__ P, int N)
{
  __shared__ short Al[64*256];     // 32 KB
  __shared__ float Wl[3][64*64];   // 48 KB
  const int wv   = threadIdx.x >> 6;
  const int lane = threadIdx.x & 63;
  const int l15  = lane & 15;
  const int lg   = lane >> 4;
  const int nb   = blockIdx.x * 64;
  const int k0   = blockIdx.y * KSL;

  const float* W; int sW, koff;
  if (k0 < K1){ W = W1; sW = sW1; koff = k0; }
  else        { W = W2; sW = sW2; koff = k0 - K1; }

  {
    const int r2  = lane >> 5;
    const int c16 = (lane & 31) * 16;
    #pragma unroll
    for (int i = 0; i < 8; ++i){
      int rbase = wv*16 + i*2;
      int row   = rbase + r2;
      const char* src = (const char*)A + (long)row*lda*2 + (long)k0*2
                        + (c16 ^ ((row & 7) << 4));
      stage16(src, (void*)(Al + rbase*256));
    }
  }

  auto STAGEW = [&](int bi, int kbase){
    #pragma unroll
    for (int i = 0; i < 4; ++i){
      int row = wv*16 + i*4 + lg;
      const char* src = (const char*)(W + (long)(nb + row)*sW + koff + kbase)
                        + ((l15*16) ^ ((row & 7) << 4));
      stage16(src, (void*)&Wl[bi][(wv*16 + i*4)*64]);
    }
  };

  STAGEW(0, 0);
  STAGEW(1, 64);
  asm volatile("s_waitcnt vmcnt(8)" ::: "memory");
  asm volatile("s_barrier" ::: "memory");

  f32x4 acc[4];
  #pragma unroll
  for (int m = 0; m < 4; ++m) acc[m] = (f32x4){0.f,0.f,0.f,0.f};

  const int  rl = wv*16 + l15;
  const int  sw = (l15 & 7) << 4;
  const char* wbase = (const char*)&Wl[0][0];
  const char* abase = (const char*)Al;

  auto COMPUTE = [&](int bi, int t){
    bf16x8 a[4][2];
    #pragma unroll
    for (int m = 0; m < 4; ++m)
      #pragma unroll
      for (int h = 0; h < 2; ++h){
        int cb = t*128 + h*64 + lg*16;
        a[m][h] = *(const bf16x8*)(abase + (m*16 + l15)*512 + (cb ^ sw));
      }
    const char* rb = wbase + bi*16384 + rl*256;
    float4 w00 = *(const float4*)(rb + ((lg*32      ) ^ sw));
    float4 w01 = *(const float4*)(rb + ((lg*32 + 16 ) ^ sw));
    float4 w10 = *(const float4*)(rb + ((lg*32 + 128) ^ sw));
    float4 w11 = *(const float4*)(rb + ((lg*32 + 144) ^ sw));
    bf16x8 wf0 = cvt8(w00, w01);
    bf16x8 wf1 = cvt8(w10, w11);
    #pragma unroll
    for (int m = 0; m < 4; ++m)
      acc[m] = __builtin_amdgcn_mfma_f32_16x16x32_bf16(a[m][0], wf0, acc[m], 0,0,0);
    #pragma unroll
    for (int m = 0; m < 4; ++m)
      acc[m] = __builtin_amdgcn_mfma_f32_16x16x32_bf16(a[m][1], wf1, acc[m], 0,0,0);
  };

  asm volatile("s_waitcnt vmcnt(4)" ::: "memory");
  COMPUTE(0, 0);
  STAGEW(2, 128);
  asm volatile("s_waitcnt vmcnt(4)" ::: "memory");
  COMPUTE(1, 1);
  STAGEW(0, 192);
  asm volatile("s_waitcnt vmcnt(4)" ::: "memory");
  COMPUTE(2, 2);
  asm volatile("s_waitcnt vmcnt(0)" ::: "memory");
  COMPUTE(0, 3);

  float* p = P + (long)blockIdx.y * 64 * N;
  #pragma unroll
  for (int mt = 0; mt < 4; ++mt)
    #pragma unroll
    for (int r = 0; r < 4; ++r){
      int m = mt*16 + lg*4 + r;
      p[(long)m * N + nb + wv*16 + l15] = acc[mt][r];
    }
}

// ---------------------------------------------------------------------------
// fc: C[64,N] = A[64,K] @ W[N,K]^T + bias.  Full K per block, no split.
// 512 threads = 8 waves x 16 N-rows = 128 cols/block. K walked in 256-wide
// chunks: A double-buffered (2x32KB), W 3-buffer rotation (3x32KB) = 160KB.
// Counted vmcnt schedule; one barrier per chunk (cross-wave A dependency).
// ---------------------------------------------------------------------------
__global__ __launch_bounds__(512) void gemm_fc(
    const short* __restrict__ A, int lda,
    const float* __restrict__ W, int sW, int K,
    const float* __restrict__ bias,
    float* __restrict__ C, int N)
{
  extern __shared__ char smem[];
  short* Al = (short*)smem;              // 2 x [64][256]
  float* Wl = (float*)(smem + 65536);    // 3 x [128][64]
  const int wv   = threadIdx.x >> 6;
  const int lane = threadIdx.x & 63;
  const int l15  = lane & 15;
  const int lg   = lane >> 4;
  const int nb   = blockIdx.x * 128;
  const int NC   = K >> 8;

  auto STAGEA = [&](int c){
    short* dst = Al + (c & 1) * 16384;
    #pragma unroll
    for (int i = 0; i < 4; ++i){
      int rbase = wv*8 + i*2;
      int row   = rbase + (lane >> 5);
      const char* src = (const char*)A + (long)row*lda*2 + (long)c*512
                        + (((lane & 31)*16) ^ ((row & 7) << 4));
      stage16(src, (void*)(dst + rbase*256));
    }
  };
  auto STAGEW = [&](int gt){
    float* dst = Wl + (gt % 3) * 8192;
    #pragma unroll
    for (int i = 0; i < 4; ++i){
      int row = wv*16 + i*4 + lg;
      const char* src = (const char*)(W + (long)(nb + row)*sW + gt*64)
                        + ((l15*16) ^ ((row & 7) << 4));
      stage16(src, (void*)(dst + (wv*16 + i*4)*64));
    }
  };

  f32x4 acc[4];
  #pragma unroll
  for (int m = 0; m < 4; ++m) acc[m] = (f32x4){0.f,0.f,0.f,0.f};

  const int rl = wv*16 + l15;
  const int sw = (l15 & 7) << 4;

  auto COMPUTE = [&](int c, int gt, int t){
    const char* abase = (const char*)(Al + (c & 1)*16384);
    bf16x8 a[4][2];
    #pragma unroll
    for (int m = 0; m < 4; ++m)
      #pragma unroll
      for (int h = 0; h < 2; ++h){
        int cb = t*128 + h*64 + lg*16;
        a[m][h] = *(const bf16x8*)(abase + (m*16 + l15)*512 + (cb ^ sw));
      }
    const char* rb = (const char*)(Wl + (gt % 3)*8192) + rl*256;
    float4 w00 = *(const float4*)(rb + ((lg*32      ) ^ sw));
    float4 w01 = *(const float4*)(rb + ((lg*32 + 16 ) ^ sw));
    float4 w10 = *(const float4*)(rb + ((lg*32 + 128) ^ sw));
    float4 w11 = *(const float4*)(rb + ((lg*32 + 144) ^ sw));
    bf16x8 wf0 = cvt8(w00, w01);
    bf16x8 wf1 = cvt8(w10, w11);
    #pragma unroll
    for (int m = 0; m < 4; ++m)
      acc[m] = __builtin_amdgcn_mfma_f32_16x16x32_bf16(a[m][0], wf0, acc[m], 0,0,0);
    #pragma unroll
    for (int m = 0; m < 4; ++m)
      acc[m] = __builtin_amdgcn_mfma_f32_16x16x32_bf16(a[m][1], wf1, acc[m], 0,0,0);
  };

  // prologue
  STAGEA(0); STAGEW(0); STAGEW(1);
  asm volatile("s_waitcnt vmcnt(8)" ::: "memory");   // A(0) done; W0,W1 in flight
  __builtin_amdgcn_s_barrier();

  for (int c = 0; c < NC-1; ++c){
    const int g = c*4;
    STAGEA(c+1);
    asm volatile("s_waitcnt vmcnt(12)" ::: "memory");  // W(g) ready
    COMPUTE(c, g, 0);   STAGEW(g+2);
    asm volatile("s_waitcnt vmcnt(12)" ::: "memory");  // W(g+1) ready
    COMPUTE(c, g+1, 1); STAGEW(g+3);
    asm volatile("s_waitcnt vmcnt(4)" ::: "memory");   // A(c+1)+W(g+2) ready
    COMPUTE(c, g+2, 2); STAGEW(g+4);
    asm volatile("s_waitcnt vmcnt(4)" ::: "memory");   // W(g+3) ready
    COMPUTE(c, g+3, 3); STAGEW(g+5);
    __builtin_amdgcn_s_barrier();
  }
  {
    const int c = NC-1, g = c*4;
    asm volatile("s_waitcnt vmcnt(4)" ::: "memory");
    COMPUTE(c, g, 0);   STAGEW(g+2);
    asm volatile("s_waitcnt vmcnt(4)" ::: "memory");
    COMPUTE(c, g+1, 1); STAGEW(g+3);
    asm volatile("s_waitcnt vmcnt(4)" ::: "memory");
    COMPUTE(c, g+2, 2);
    asm volatile("s_waitcnt vmcnt(0)" ::: "memory");
    COMPUTE(c, g+3, 3);
  }

  const int col = nb + wv*16 + l15;
  const float bn = bias[col];
  #pragma unroll
  for (int mt = 0; mt < 4; ++mt)
    #pragma unroll
    for (int r = 0; r < 4; ++r){
      int m = mt*16 + lg*4 + r;
      C[(long)m * N + col] = acc[mt][r] + bn;
    }
}

// ---------------------------------------------------------------------------
// energy: T = encbf @ Wbf^T, scores[m] += v . tanh(T + hproj[b,n])
// hproj = sum of 4 split-K partials (Ph) + attn_b, folded inline.
// grid 1024: m3 = bx&127 (fast -> XCD id) for enc L2 reuse.
// ---------------------------------------------------------------------------
__global__ __launch_bounds__(256) void energy_k(
    const short* __restrict__ encbf, const short* __restrict__ Wbf,
    const float* __restrict__ Ph, const float* __restrict__ attn_b,
    const float* __restrict__ v_w, float* __restrict__ scores)
{
  const int bx = blockIdx.x;
  const int m3 = bx & 127, n3 = bx >> 7;
  const int wave = threadIdx.x >> 6;
  const int lane = threadIdx.x & 63;
  const int l15  = lane & 15;
  const int lg   = lane >> 4;
  const int mb   = m3 * 64;
  const int nb   = n3 * 64 + wave * 16;
  const int b    = mb >> 7;

  const int hi = b*512 + nb + l15;
  const float hp = attn_b[nb + l15] + Ph[hi] + Ph[32768 + hi]
                 + Ph[65536 + hi] + Ph[98304 + hi];

  f32x4 acc[4] = {};
  const short* ap  = encbf + (long)(mb + l15) * 1024 + lg * 8;
  const short* wpb = Wbf   + (long)(nb + l15) * 1024 + lg * 8;

  bf16x8 wn  = *(const bf16x8*)(wpb);
  bf16x8 an0 = *(const bf16x8*)(ap);
  bf16x8 an1 = *(const bf16x8*)(ap + 16*1024);
  bf16x8 an2 = *(const bf16x8*)(ap + 32*1024);
  bf16x8 an3 = *(const bf16x8*)(ap + 48*1024);
  for (int kb = 32; kb < 1024; kb += 32){
    bf16x8 wc = wn, c0 = an0, c1 = an1, c2 = an2, c3 = an3;
    wn  = *(const bf16x8*)(wpb + kb);
    an0 = *(const bf16x8*)(ap + kb);
    an1 = *(const bf16x8*)(ap + kb + 16*1024);
    an2 = *(const bf16x8*)(ap + kb + 32*1024);
    an3 = *(const bf16x8*)(ap + kb + 48*1024);
    acc[0] = __builtin_amdgcn_mfma_f32_16x16x32_bf16(c0, wc, acc[0], 0,0,0);
    acc[1] = __builtin_amdgcn_mfma_f32_16x16x32_bf16(c1, wc, acc[1], 0,0,0);
    acc[2] = __builtin_amdgcn_mfma_f32_16x16x32_bf16(c2, wc, acc[2], 0,0,0);
    acc[3] = __builtin_amdgcn_mfma_f32_16x16x32_bf16(c3, wc, acc[3], 0,0,0);
  }
  acc[0] = __builtin_amdgcn_mfma_f32_16x16x32_bf16(an0, wn, acc[0], 0,0,0);
  acc[1] = __builtin_amdgcn_mfma_f32_16x16x32_bf16(an1, wn, acc[1], 0,0,0);
  acc[2] = __builtin_amdgcn_mfma_f32_16x16x32_bf16(an2, wn, acc[2], 0,0,0);
  acc[3] = __builtin_amdgcn_mfma_f32_16x16x32_bf16(an3, wn, acc[3], 0,0,0);

  const float vn = v_w[nb + l15];
  #pragma unroll
  for (int mt = 0; mt < 4; ++mt){
    #pragma unroll
    for (int r = 0; r < 4; ++r){
      int m = mb + mt*16 + lg*4 + r;
      float e = fast_tanh(acc[mt][r] + hp) * vn;
      e += __shfl_xor(e, 1, 16);
      e += __shfl_xor(e, 2, 16);
      e += __shfl_xor(e, 4, 16);
      e += __shfl_xor(e, 8, 16);
      if (l15 == 0) atomicAdd(&scores[m], e);
    }
  }
}

// Fused masked softmax + context
__global__ __launch_bounds__(256) void ctxsm_k(
    const float* __restrict__ sco, const int* __restrict__ mask,
    const short* __restrict__ encbf, float* __restrict__ aw,
    short* __restrict__ A0, short* __restrict__ Zb)
{
  const int bb = blockIdx.x;
  const int t  = threadIdx.x;
  __shared__ float red[128];
  __shared__ float w[128];
  float v = 0.f;
  if (t < 128){
    v = sco[bb*128 + t];
    if (mask[bb*128 + t] == 0) v = -1e10f;
    red[t] = v;
  }
  __syncthreads();
  for (int d = 64; d > 0; d >>= 1){
    if (t < d) red[t] = fmaxf(red[t], red[t + d]);
    __syncthreads();
  }
  const float mx = red[0];
  __syncthreads();
  if (t < 128){
    float e = __expf(v - mx);
    w[t] = e; red[t] = e;
  }
  __syncthreads();
  for (int d = 64; d > 0; d >>= 1){
    if (t < d) red[t] += red[t + d];
    __syncthreads();
  }
  const float inv = 1.f / red[0];
  if (blockIdx.y == 0 && t < 128) aw[bb*128 + t] = w[t] * inv;

  const int dd = blockIdx.y * 256 + t;
  const unsigned short* e = (const unsigned short*)encbf + (long)bb*131072 + dd;
  float s = 0.f;
  #pragma unroll 4
  for (int si = 0; si < 128; ++si){
    float ev = __builtin_bit_cast(float, (unsigned)e[si*1024] << 16);
    s += w[si] * ev;
  }
  s *= inv;
  short vbf = f2bf(s);
  A0[bb*2560 + 512  + dd] = vbf;
  Zb[bb*2560 + 1024 + dd] = vbf;
}

// LSTM epilogue with fused split-K reduce
__global__ __launch_bounds__(256) void lstm_k(
    const float* __restrict__ P, int KS,
    const float* __restrict__ bi, const float* __restrict__ bh,
    const float* __restrict__ c_prev,
    float* __restrict__ h_out, float* __restrict__ c_out,
    short* __restrict__ h_bf, int bf_stride)
{
  const int i = blockIdx.x * 256 + threadIdx.x;
  const int b = i >> 10, n = i & 1023;
  float g4[4];
  #pragma unroll
  for (int gi = 0; gi < 4; ++gi){
    int col = gi*1024 + n;
    float s = bi[col] + bh[col];
    const float* p = P + (long)b*4096 + col;
    for (int sl = 0; sl < KS; ++sl) s += p[(long)sl * 262144];
    g4[gi] = s;
  }
  float iv = fast_sig (g4[0]);
  float fv = fast_sig (g4[1]);
  float gv = fast_tanh(g4[2]);
  float ov = fast_sig (g4[3]);
  float c = fv * c_prev[i] + iv * gv;
  float h = ov * fast_tanh(c);
  c_out[i] = c;
  h_out[i] = h;
  h_bf[(long)b * bf_stride + n] = f2bf(h);
}

extern "C" void kernel_launch(void* const* d_in, const int* in_sizes, int n_in,
                              void* d_out, int out_size, void* d_ws, size_t ws_size,
                              hipStream_t stream)
{
  const int*   tok    = (const int*)  d_in[0];
  const float* hidden = (const float*)d_in[1];
  const float* cell   = (const float*)d_in[2];
  const float* enc    = (const float*)d_in[3];
  const int*   mask   = (const int*)  d_in[4];
  const float* emb    = (const float*)d_in[5];
  const float* attn_w = (const float*)d_in[6];
  const float* attn_b = (const float*)d_in[7];
  const float* v_w    = (const float*)d_in[8];
  const float* w_ih0  = (const float*)d_in[9];
  const float* w_hh0  = (const float*)d_in[10];
  const float* b_ih0  = (const float*)d_in[11];
  const float* b_hh0  = (const float*)d_in[12];
  const float* w_ih1  = (const float*)d_in[13];
  const float* w_hh1  = (const float*)d_in[14];
  const float* b_ih1  = (const float*)d_in[15];
  const float* b_hh1  = (const float*)d_in[16];
  const float* fc_w   = (const float*)d_in[17];
  const float* fc_b   = (const float*)d_in[18];

  float* out  = (float*)d_out;
  float* pred = out;                 // [64,32000]
  float* nh   = out + 2048000;       // [2,64,1024]
  float* nc   = out + 2179072;       // [2,64,1024]
  float* aw   = out + 2310144;       // [64,128]

  char*  wsb   = (char*)d_ws;
  short* encbf = (short*)(wsb + 0);          // 16,777,216 B
  short* Wbf   = (short*)(wsb + 16777216);   //  1,048,576 B
  short* A0    = (short*)(wsb + 17825792);   //    327,680 B
  short* A1    = (short*)(wsb + 18153472);   //    262,144 B
  short* Zb    = (short*)(wsb + 18415616);   //    327,680 B
  float* sco   = (float*)(wsb + 18743296);   //     32,768 B
  float* Pb    = (float*)(wsb + 18776064);   // partials (hproj 4 / gates 10)

  hipFuncSetAttribute((const void*)gemm_fc,
                      hipFuncAttributeMaxDynamicSharedMemorySize, 163840);

  prep_all<<<4404, 256, 0, stream>>>(tok, emb, hidden, enc, attn_w,
                                     encbf, Wbf, A0, A1, Zb, sco);

  // hproj partials = h_top @ attn_w[:,0:1024]^T  (4 x 256-k slices)
  gemm_lds<<<dim3(8, 4), 256, 0, stream>>>(A1 + 1024, 2048,
                                           attn_w, 2048, 1<<30, nullptr, 0,
                                           Pb, 512);

  energy_k<<<1024, 256, 0, stream>>>(encbf, Wbf, Pb, attn_b, v_w, sco);

  ctxsm_k<<<dim3(64, 4), 256, 0, stream>>>(sco, mask, encbf, aw, A0, Zb);

  // layer 0: A0 = [emb | ctx | h0_prev], W = [w_ih0 | w_hh0], K=2560
  gemm_lds<<<dim3(64, 10), 256, 0, stream>>>(A0, 2560,
                                             w_ih0, 1536, 1536, w_hh0, 1024,
                                             Pb, 4096);
  lstm_k<<<256, 256, 0, stream>>>(Pb, 10, b_ih0, b_hh0, cell,
                                  nh, nc, A1, 2048);

  // layer 1: A1 = [h0' | h1_prev], W = [w_ih1 | w_hh1], K=2048
  gemm_lds<<<dim3(64, 8), 256, 0, stream>>>(A1, 2048,
                                            w_ih1, 1024, 1024, w_hh1, 1024,
                                            Pb, 4096);
  lstm_k<<<256, 256, 0, stream>>>(Pb, 8, b_ih1, b_hh1, cell + 65536,
                                  nh + 65536, nc + 65536, Zb, 2560);

  // prediction = Zb @ fc_w^T + fc_b  (full-K, direct output)
  gemm_fc<<<250, 512, 163840, stream>>>(Zb, 2560, fc_w, 2560, 2560,
                                        fc_b, pred, 32000);
}